// Round 1
// baseline (1426.627 us; speedup 1.0000x reference)
//
#include <hip/hip_runtime.h>

#define H 64
#define N_PERSON 200000
#define N_MOVIE 100000
#define E_ACTED 1600000
#define E_DIRECTED 200000
#define E_WWW 3200000
#define N_LAYERS 2

// ---------------- CSR build ----------------

static __global__ __launch_bounds__(256) void hist_k(const int* __restrict__ dst, int E,
                                                     int* __restrict__ cnt) {
  int e = blockIdx.x * 256 + threadIdx.x;
  if (e < E) atomicAdd(&cnt[dst[e]], 1);
}

// exclusive block scan; also emits block totals. Safe to call in-place (out==in) with 1 block.
static __global__ __launch_bounds__(1024) void scan_block_k(const int* __restrict__ in, int n,
                                                            int* __restrict__ out,
                                                            int* __restrict__ partials) {
  __shared__ int sm[1024];
  int tid = threadIdx.x;
  int gid = blockIdx.x * 1024 + tid;
  int v = (gid < n) ? in[gid] : 0;
  sm[tid] = v;
  __syncthreads();
  for (int d = 1; d < 1024; d <<= 1) {
    int t = (tid >= d) ? sm[tid - d] : 0;
    __syncthreads();
    if (tid >= d) sm[tid] += t;
    __syncthreads();
  }
  if (gid < n) out[gid] = sm[tid] - v;  // exclusive
  if (tid == 1023 && partials) partials[blockIdx.x] = sm[1023];
}

static __global__ __launch_bounds__(1024) void add_off_k(int* __restrict__ off, int n,
                                                         const int* __restrict__ parts, int total) {
  int gid = blockIdx.x * 1024 + threadIdx.x;
  if (gid < n) off[gid] += parts[gid >> 10];
  else if (gid == n) off[gid] = total;
}

static __global__ __launch_bounds__(256) void scatter_k(const int* __restrict__ src,
                                                        const int* __restrict__ dst, int E,
                                                        int* __restrict__ cur,
                                                        int* __restrict__ csr) {
  int e = blockIdx.x * 256 + threadIdx.x;
  if (e < E) {
    int pos = atomicAdd(&cur[dst[e]], 1);
    csr[pos] = src[e];
  }
}

// ---------------- pull mean (one wave per dst node) ----------------

static __global__ __launch_bounds__(256) void pull_mean_k(const float* __restrict__ xsrc,
                                                          const int* __restrict__ off,
                                                          const int* __restrict__ csr, int n_dst,
                                                          float* __restrict__ meanout) {
  int wid = (blockIdx.x * 256 + threadIdx.x) >> 6;
  int lane = threadIdx.x & 63;
  if (wid >= n_dst) return;
  int e0 = off[wid], e1 = off[wid + 1];
  float a0 = 0.f, a1 = 0.f, a2 = 0.f, a3 = 0.f;
  int e = e0;
  for (; e + 4 <= e1; e += 4) {
    int s0 = csr[e], s1 = csr[e + 1], s2 = csr[e + 2], s3 = csr[e + 3];
    a0 += xsrc[s0 * 64 + lane];
    a1 += xsrc[s1 * 64 + lane];
    a2 += xsrc[s2 * 64 + lane];
    a3 += xsrc[s3 * 64 + lane];
  }
  for (; e < e1; ++e) a0 += xsrc[csr[e] * 64 + lane];
  float s = (a0 + a1) + (a2 + a3);
  float c = (float)(e1 - e0);
  meanout[wid * 64 + lane] = s / fmaxf(c, 1.0f);
}

// ---------------- fp32 GEMM: C[M x 64] = A[M x 64] @ W^T (+W2^T) (+bias) (+Cin) (relu) ----------------

static __global__ __launch_bounds__(256) void gemm_k64(const float* __restrict__ A, int M,
                                                       const float* __restrict__ W,
                                                       const float* __restrict__ W2,
                                                       const float* __restrict__ bias,
                                                       const float* __restrict__ Cin,
                                                       float* __restrict__ Cout, int relu) {
  __shared__ float At[64 * 132];  // At[k*132 + row], row in [0,128)
  __shared__ float Wt[64 * 68];   // Wt[k*68  + j],   j   in [0,64)
  const int t = threadIdx.x;
  const int m0 = blockIdx.x * 128;

  // stage W (+W2) k-major: Wt[k][j] = W[j][k]
  for (int i = 0; i < 4; ++i) {
    int f = i * 256 + t;  // [0,1024)
    int j = f & 63;
    int c4 = f >> 6;  // [0,16)
    float4 v = *(const float4*)(W + j * 64 + c4 * 4);
    if (W2) {
      float4 v2 = *(const float4*)(W2 + j * 64 + c4 * 4);
      v.x += v2.x; v.y += v2.y; v.z += v2.z; v.w += v2.w;
    }
    Wt[(c4 * 4 + 0) * 68 + j] = v.x;
    Wt[(c4 * 4 + 1) * 68 + j] = v.y;
    Wt[(c4 * 4 + 2) * 68 + j] = v.z;
    Wt[(c4 * 4 + 3) * 68 + j] = v.w;
  }
  // stage A k-major: At[k][row] = A[m0+row][k]
  for (int i = 0; i < 8; ++i) {
    int f = i * 256 + t;  // [0,2048)
    int row = f & 127;
    int c4 = f >> 7;  // [0,16)
    int m = m0 + row;
    float4 v = make_float4(0.f, 0.f, 0.f, 0.f);
    if (m < M) v = *(const float4*)(A + (size_t)m * 64 + c4 * 4);
    At[(c4 * 4 + 0) * 132 + row] = v.x;
    At[(c4 * 4 + 1) * 132 + row] = v.y;
    At[(c4 * 4 + 2) * 132 + row] = v.z;
    At[(c4 * 4 + 3) * 132 + row] = v.w;
  }
  __syncthreads();

  const int tc = t & 15;  // cols tc*4..tc*4+3
  const int tr = t >> 4;  // rows tr*8..tr*8+7
  float acc[8][4];
#pragma unroll
  for (int r = 0; r < 8; ++r)
#pragma unroll
    for (int c = 0; c < 4; ++c) acc[r][c] = 0.f;

#pragma unroll 8
  for (int k = 0; k < 64; ++k) {
    float4 w = *(const float4*)(&Wt[k * 68 + tc * 4]);
    float4 a0 = *(const float4*)(&At[k * 132 + tr * 8]);
    float4 a1 = *(const float4*)(&At[k * 132 + tr * 8 + 4]);
    float av[8] = {a0.x, a0.y, a0.z, a0.w, a1.x, a1.y, a1.z, a1.w};
    float wv[4] = {w.x, w.y, w.z, w.w};
#pragma unroll
    for (int r = 0; r < 8; ++r)
#pragma unroll
      for (int c = 0; c < 4; ++c) acc[r][c] = fmaf(av[r], wv[c], acc[r][c]);
  }

  float4 bv = make_float4(0.f, 0.f, 0.f, 0.f);
  if (bias) bv = *(const float4*)(bias + tc * 4);
#pragma unroll
  for (int r = 0; r < 8; ++r) {
    int m = m0 + tr * 8 + r;
    if (m < M) {
      float4 o;
      o.x = acc[r][0] + bv.x;
      o.y = acc[r][1] + bv.y;
      o.z = acc[r][2] + bv.z;
      o.w = acc[r][3] + bv.w;
      if (Cin) {
        float4 ci = *(const float4*)(Cin + (size_t)m * 64 + tc * 4);
        o.x += ci.x; o.y += ci.y; o.z += ci.z; o.w += ci.w;
      }
      if (relu) {
        o.x = fmaxf(o.x, 0.f); o.y = fmaxf(o.y, 0.f);
        o.z = fmaxf(o.z, 0.f); o.w = fmaxf(o.w, 0.f);
      }
      *(float4*)(Cout + (size_t)m * 64 + tc * 4) = o;
    }
  }
}

// ---------------- final projection ----------------

static __global__ __launch_bounds__(256) void final_k(const float* __restrict__ xm,
                                                      const float* __restrict__ linW,
                                                      const float* __restrict__ linb,
                                                      float* __restrict__ out, int n) {
  int wid = (blockIdx.x * 256 + threadIdx.x) >> 6;
  int lane = threadIdx.x & 63;
  if (wid >= n) return;
  float v = xm[wid * 64 + lane] * linW[lane];
  for (int o = 32; o > 0; o >>= 1) v += __shfl_down(v, o, 64);
  if (lane == 0) out[wid] = v + linb[0];
}

// ---------------- launch ----------------

extern "C" void kernel_launch(void* const* d_in, const int* in_sizes, int n_in, void* d_out,
                              int out_size, void* d_ws, size_t ws_size, hipStream_t stream) {
  const float* x_person = (const float*)d_in[0];
  const float* x_movie = (const float*)d_in[1];
  const int* acted_src = (const int*)d_in[2];
  const int* acted_dst = (const int*)d_in[3];
  const int* directed_src = (const int*)d_in[4];
  const int* directed_dst = (const int*)d_in[5];
  const int* www_src = (const int*)d_in[6];
  const int* www_dst = (const int*)d_in[7];
  const float* Wl_acted = (const float*)d_in[8];
  const float* bl_acted = (const float*)d_in[9];
  const float* Wr_acted = (const float*)d_in[10];
  const float* Wl_directed = (const float*)d_in[11];
  const float* bl_directed = (const float*)d_in[12];
  const float* Wr_directed = (const float*)d_in[13];
  const float* Wl_www = (const float*)d_in[14];
  const float* bl_www = (const float*)d_in[15];
  const float* Wr_www = (const float*)d_in[16];
  const float* lin_W = (const float*)d_in[17];
  const float* lin_b = (const float*)d_in[18];
  float* out = (float*)d_out;

  char* base = (char*)d_ws;
  size_t pos = 0;
  auto carve = [&](size_t b) -> void* {
    void* r = base + pos;
    pos += (b + 255) & ~(size_t)255;
    return r;
  };
  int* off_a = (int*)carve((N_MOVIE + 1) * sizeof(int));
  int* cur_a = (int*)carve((N_MOVIE + 1) * sizeof(int));
  int* off_d = (int*)carve((N_MOVIE + 1) * sizeof(int));
  int* cur_d = (int*)carve((N_MOVIE + 1) * sizeof(int));
  int* off_w = (int*)carve((N_PERSON + 1) * sizeof(int));
  int* cur_w = (int*)carve((N_PERSON + 1) * sizeof(int));
  int* parts = (int*)carve(1024 * sizeof(int));
  int* csr_a = (int*)carve((size_t)E_ACTED * sizeof(int));
  int* csr_d = (int*)carve((size_t)E_DIRECTED * sizeof(int));
  int* csr_w = (int*)carve((size_t)E_WWW * sizeof(int));
  float* meanbuf = (float*)carve((size_t)N_PERSON * H * sizeof(float));
  float* xp0 = (float*)carve((size_t)N_PERSON * H * sizeof(float));
  float* xp1 = (float*)carve((size_t)N_PERSON * H * sizeof(float));
  float* xm0 = (float*)carve((size_t)N_MOVIE * H * sizeof(float));
  float* xm1 = (float*)carve((size_t)N_MOVIE * H * sizeof(float));
  (void)ws_size; (void)in_sizes; (void)n_in; (void)out_size;

  auto build = [&](const int* src, const int* dstp, int E, int n, int* off, int* cur, int* csr) {
    hipMemsetAsync(cur, 0, (size_t)n * sizeof(int), stream);
    hist_k<<<(E + 255) / 256, 256, 0, stream>>>(dstp, E, cur);
    int nb = (n + 1023) / 1024;
    scan_block_k<<<nb, 1024, 0, stream>>>(cur, n, off, parts);
    scan_block_k<<<1, 1024, 0, stream>>>(parts, nb, parts, nullptr);
    add_off_k<<<(n + 1 + 1023) / 1024, 1024, 0, stream>>>(off, n, parts, E);
    hipMemcpyAsync(cur, off, (size_t)n * sizeof(int), hipMemcpyDeviceToDevice, stream);
    scatter_k<<<(E + 255) / 256, 256, 0, stream>>>(src, dstp, E, cur, csr);
  };

  build(acted_src, acted_dst, E_ACTED, N_MOVIE, off_a, cur_a, csr_a);
  build(directed_src, directed_dst, E_DIRECTED, N_MOVIE, off_d, cur_d, csr_d);
  build(www_src, www_dst, E_WWW, N_PERSON, off_w, cur_w, csr_w);

  auto gemm = [&](const float* A, int M, const float* W, const float* W2, const float* bias,
                  const float* Cin, float* Cout, int relu) {
    gemm_k64<<<(M + 127) / 128, 256, 0, stream>>>(A, M, W, W2, bias, Cin, Cout, relu);
  };
  auto pull = [&](const float* xsrc, const int* off, const int* csr, int n, float* mo) {
    pull_mean_k<<<(n + 3) / 4, 256, 0, stream>>>(xsrc, off, csr, n, mo);
  };

  const float* xp_cur = x_person;
  const float* xm_cur = x_movie;
  float* xp_buf[2] = {xp0, xp1};
  float* xm_buf[2] = {xm0, xm1};

  for (int l = 0; l < N_LAYERS; ++l) {
    float* xm_new = xm_buf[l];
    float* xp_new = xp_buf[l];
    const float* WlA = Wl_acted + l * 64 * 64;
    const float* WrA = Wr_acted + l * 64 * 64;
    const float* WlD = Wl_directed + l * 64 * 64;
    const float* WrD = Wr_directed + l * 64 * 64;
    const float* WlW = Wl_www + l * 64 * 64;
    const float* WrW = Wr_www + l * 64 * 64;
    const float* bA = bl_acted + l * 64;
    const float* bD = bl_directed + l * 64;
    const float* bW = bl_www + l * 64;

    // movie = relu( mean_acted@WlA^T + bA + mean_dir@WlD^T + bD + x_m@(WrA+WrD)^T )
    pull(xp_cur, off_a, csr_a, N_MOVIE, meanbuf);
    gemm(meanbuf, N_MOVIE, WlA, nullptr, bA, nullptr, xm_new, 0);
    pull(xp_cur, off_d, csr_d, N_MOVIE, meanbuf);
    gemm(meanbuf, N_MOVIE, WlD, nullptr, bD, xm_new, xm_new, 0);
    gemm(xm_cur, N_MOVIE, WrA, WrD, nullptr, xm_new, xm_new, 1);

    // person = relu( mean_www@WlW^T + bW + x_p@WrW^T )
    pull(xp_cur, off_w, csr_w, N_PERSON, meanbuf);
    gemm(meanbuf, N_PERSON, WlW, nullptr, bW, nullptr, xp_new, 0);
    gemm(xp_cur, N_PERSON, WrW, nullptr, nullptr, xp_new, xp_new, 1);

    xp_cur = xp_new;
    xm_cur = xm_new;
  }

  final_k<<<(N_MOVIE + 3) / 4, 256, 0, stream>>>(xm_cur, lin_W, lin_b, out, N_MOVIE);
}

// Round 2
// 859.599 us; speedup vs baseline: 1.6596x; 1.6596x over previous
//
#include <hip/hip_runtime.h>

#define H 64
#define N_PERSON 200000
#define N_MOVIE 100000
#define E_ACTED 1600000
#define E_DIRECTED 200000
#define E_WWW 3200000
#define N_LAYERS 2

#define SH 8          // bucket = dst >> 8 (256 dsts per bucket)
#define CH 16384      // edges per partition block

// ---------------- scan helpers ----------------

static __global__ __launch_bounds__(1024) void scan_block_k(const int* __restrict__ in, int n,
                                                            int* __restrict__ out,
                                                            int* __restrict__ partials) {
  __shared__ int sm[1024];
  int tid = threadIdx.x;
  int gid = blockIdx.x * 1024 + tid;
  int v = (gid < n) ? in[gid] : 0;
  sm[tid] = v;
  __syncthreads();
  for (int d = 1; d < 1024; d <<= 1) {
    int t = (tid >= d) ? sm[tid - d] : 0;
    __syncthreads();
    if (tid >= d) sm[tid] += t;
    __syncthreads();
  }
  if (gid < n) out[gid] = sm[tid] - v;  // exclusive
  if (tid == 1023 && partials) partials[blockIdx.x] = sm[1023];
}

static __global__ __launch_bounds__(1024) void add_off_k(int* __restrict__ off, int n,
                                                         const int* __restrict__ parts, int total) {
  int gid = blockIdx.x * 1024 + threadIdx.x;
  if (gid < n) off[gid] += parts[gid >> 10];
  else if (gid == n) off[gid] = total;
}

// ---------------- two-level counting sort CSR build ----------------

static __global__ __launch_bounds__(256) void part_count_k(const int* __restrict__ dst, int E,
                                                           int nblk, int nbuk,
                                                           int* __restrict__ counts) {
  __shared__ int hist[800];
  int blk = blockIdx.x, t = threadIdx.x;
  for (int i = t; i < nbuk; i += 256) hist[i] = 0;
  __syncthreads();
  int e0 = blk * CH, e1 = min(e0 + CH, E);
  for (int e = e0 + t; e < e1; e += 256) atomicAdd(&hist[dst[e] >> SH], 1);
  __syncthreads();
  for (int i = t; i < nbuk; i += 256) counts[(size_t)i * nblk + blk] = hist[i];
}

static __global__ __launch_bounds__(256) void part_scatter_k(const int* __restrict__ src,
                                                             const int* __restrict__ dst, int E,
                                                             int nblk, int nbuk,
                                                             const int* __restrict__ off_bb,
                                                             int2* __restrict__ pairs) {
  __shared__ int cur[800];
  int blk = blockIdx.x, t = threadIdx.x;
  for (int i = t; i < nbuk; i += 256) cur[i] = off_bb[(size_t)i * nblk + blk];
  __syncthreads();
  int e0 = blk * CH, e1 = min(e0 + CH, E);
  for (int e = e0 + t; e < e1; e += 256) {
    int d = dst[e];
    int pos = atomicAdd(&cur[d >> SH], 1);
    pairs[pos] = make_int2(d, src[e]);
  }
}

static __global__ __launch_bounds__(256) void fine_sort_k(const int2* __restrict__ pairs, int E,
                                                          int nblk, int nbuk, int N,
                                                          const int* __restrict__ off_bb,
                                                          int* __restrict__ off,
                                                          int* __restrict__ csr) {
  __shared__ int hist[256];
  __shared__ int sc[256];
  int b = blockIdx.x, t = threadIdx.x;
  int bstart = off_bb[(size_t)b * nblk];
  int bend = off_bb[(size_t)(b + 1) * nblk];  // off_bb[nbuk*nblk] == E
  int base = b << SH;
  hist[t] = 0;
  __syncthreads();
  for (int e = bstart + t; e < bend; e += 256) atomicAdd(&hist[pairs[e].x - base], 1);
  __syncthreads();
  sc[t] = hist[t];
  __syncthreads();
  for (int d = 1; d < 256; d <<= 1) {
    int u = (t >= d) ? sc[t - d] : 0;
    __syncthreads();
    sc[t] += u;
    __syncthreads();
  }
  int excl = sc[t] - hist[t];
  if (base + t < N) off[base + t] = bstart + excl;
  if (b == nbuk - 1 && t == 0) off[N] = E;
  hist[t] = excl;  // reuse as cursor
  __syncthreads();
  for (int e = bstart + t; e < bend; e += 256) {
    int2 p = pairs[e];
    int pos = bstart + atomicAdd(&hist[p.x - base], 1);
    csr[pos] = p.y;
  }
}

// ---------------- pull mean (one wave per dst node) ----------------

static __global__ __launch_bounds__(256) void pull_mean_k(const float* __restrict__ xsrc,
                                                          const int* __restrict__ off,
                                                          const int* __restrict__ csr, int n_dst,
                                                          float* __restrict__ meanout) {
  int wid = (blockIdx.x * 256 + threadIdx.x) >> 6;
  int lane = threadIdx.x & 63;
  if (wid >= n_dst) return;
  int e0 = off[wid], e1 = off[wid + 1];
  float a0 = 0.f, a1 = 0.f, a2 = 0.f, a3 = 0.f;
  int e = e0;
  for (; e + 4 <= e1; e += 4) {
    int s0 = csr[e], s1 = csr[e + 1], s2 = csr[e + 2], s3 = csr[e + 3];
    a0 += xsrc[s0 * 64 + lane];
    a1 += xsrc[s1 * 64 + lane];
    a2 += xsrc[s2 * 64 + lane];
    a3 += xsrc[s3 * 64 + lane];
  }
  for (; e < e1; ++e) a0 += xsrc[csr[e] * 64 + lane];
  float s = (a0 + a1) + (a2 + a3);
  float c = (float)(e1 - e0);
  meanout[wid * 64 + lane] = s / fmaxf(c, 1.0f);
}

// ---------------- fused fp32 GEMM: C = sum_s A_s @ (W_s [+Wadd])^T + b0 + b1, relu ----------------

static __global__ __launch_bounds__(256) void gemm_fused_k(
    int M, int nsrc, const float* __restrict__ A0, const float* __restrict__ A1,
    const float* __restrict__ A2, const float* __restrict__ W0, const float* __restrict__ W1,
    const float* __restrict__ W2, const float* __restrict__ Wadd,
    const float* __restrict__ bias0, const float* __restrict__ bias1, float* __restrict__ Cout,
    int relu) {
  __shared__ float At[64 * 132];  // At[k*132 + row]
  __shared__ float Wt[64 * 68];   // Wt[k*68 + j]
  const float* As[3] = {A0, A1, A2};
  const float* Ws[3] = {W0, W1, W2};
  const int t = threadIdx.x;
  const int m0 = blockIdx.x * 128;
  const int tc = t & 15;
  const int tr = t >> 4;
  float acc[8][4];
#pragma unroll
  for (int r = 0; r < 8; ++r)
#pragma unroll
    for (int c = 0; c < 4; ++c) acc[r][c] = 0.f;

  for (int s = 0; s < nsrc; ++s) {
    if (s) __syncthreads();
    const float* W = Ws[s];
    const float* Wa = (s == nsrc - 1) ? Wadd : nullptr;
    for (int i = 0; i < 4; ++i) {
      int f = i * 256 + t;
      int j = f & 63;
      int c4 = f >> 6;
      float4 v = *(const float4*)(W + j * 64 + c4 * 4);
      if (Wa) {
        float4 v2 = *(const float4*)(Wa + j * 64 + c4 * 4);
        v.x += v2.x; v.y += v2.y; v.z += v2.z; v.w += v2.w;
      }
      Wt[(c4 * 4 + 0) * 68 + j] = v.x;
      Wt[(c4 * 4 + 1) * 68 + j] = v.y;
      Wt[(c4 * 4 + 2) * 68 + j] = v.z;
      Wt[(c4 * 4 + 3) * 68 + j] = v.w;
    }
    const float* A = As[s];
    for (int i = 0; i < 8; ++i) {
      int f = i * 256 + t;
      int row = f & 127;
      int c4 = f >> 7;
      int m = m0 + row;
      float4 v = make_float4(0.f, 0.f, 0.f, 0.f);
      if (m < M) v = *(const float4*)(A + (size_t)m * 64 + c4 * 4);
      At[(c4 * 4 + 0) * 132 + row] = v.x;
      At[(c4 * 4 + 1) * 132 + row] = v.y;
      At[(c4 * 4 + 2) * 132 + row] = v.z;
      At[(c4 * 4 + 3) * 132 + row] = v.w;
    }
    __syncthreads();

#pragma unroll 8
    for (int k = 0; k < 64; ++k) {
      float4 w = *(const float4*)(&Wt[k * 68 + tc * 4]);
      float4 a0 = *(const float4*)(&At[k * 132 + tr * 8]);
      float4 a1 = *(const float4*)(&At[k * 132 + tr * 8 + 4]);
      float av[8] = {a0.x, a0.y, a0.z, a0.w, a1.x, a1.y, a1.z, a1.w};
      float wv[4] = {w.x, w.y, w.z, w.w};
#pragma unroll
      for (int r = 0; r < 8; ++r)
#pragma unroll
        for (int c = 0; c < 4; ++c) acc[r][c] = fmaf(av[r], wv[c], acc[r][c]);
    }
  }

  float4 bv = make_float4(0.f, 0.f, 0.f, 0.f);
  if (bias0) {
    float4 b0 = *(const float4*)(bias0 + tc * 4);
    bv.x += b0.x; bv.y += b0.y; bv.z += b0.z; bv.w += b0.w;
  }
  if (bias1) {
    float4 b1 = *(const float4*)(bias1 + tc * 4);
    bv.x += b1.x; bv.y += b1.y; bv.z += b1.z; bv.w += b1.w;
  }
#pragma unroll
  for (int r = 0; r < 8; ++r) {
    int m = m0 + tr * 8 + r;
    if (m < M) {
      float4 o;
      o.x = acc[r][0] + bv.x;
      o.y = acc[r][1] + bv.y;
      o.z = acc[r][2] + bv.z;
      o.w = acc[r][3] + bv.w;
      if (relu) {
        o.x = fmaxf(o.x, 0.f); o.y = fmaxf(o.y, 0.f);
        o.z = fmaxf(o.z, 0.f); o.w = fmaxf(o.w, 0.f);
      }
      *(float4*)(Cout + (size_t)m * 64 + tc * 4) = o;
    }
  }
}

// ---------------- final projection ----------------

static __global__ __launch_bounds__(256) void final_k(const float* __restrict__ xm,
                                                      const float* __restrict__ linW,
                                                      const float* __restrict__ linb,
                                                      float* __restrict__ out, int n) {
  int wid = (blockIdx.x * 256 + threadIdx.x) >> 6;
  int lane = threadIdx.x & 63;
  if (wid >= n) return;
  float v = xm[wid * 64 + lane] * linW[lane];
  for (int o = 32; o > 0; o >>= 1) v += __shfl_down(v, o, 64);
  if (lane == 0) out[wid] = v + linb[0];
}

// ---------------- launch ----------------

extern "C" void kernel_launch(void* const* d_in, const int* in_sizes, int n_in, void* d_out,
                              int out_size, void* d_ws, size_t ws_size, hipStream_t stream) {
  const float* x_person = (const float*)d_in[0];
  const float* x_movie = (const float*)d_in[1];
  const int* acted_src = (const int*)d_in[2];
  const int* acted_dst = (const int*)d_in[3];
  const int* directed_src = (const int*)d_in[4];
  const int* directed_dst = (const int*)d_in[5];
  const int* www_src = (const int*)d_in[6];
  const int* www_dst = (const int*)d_in[7];
  const float* Wl_acted = (const float*)d_in[8];
  const float* bl_acted = (const float*)d_in[9];
  const float* Wr_acted = (const float*)d_in[10];
  const float* Wl_directed = (const float*)d_in[11];
  const float* bl_directed = (const float*)d_in[12];
  const float* Wr_directed = (const float*)d_in[13];
  const float* Wl_www = (const float*)d_in[14];
  const float* bl_www = (const float*)d_in[15];
  const float* Wr_www = (const float*)d_in[16];
  const float* lin_W = (const float*)d_in[17];
  const float* lin_b = (const float*)d_in[18];
  float* out = (float*)d_out;
  (void)in_sizes; (void)n_in; (void)out_size; (void)ws_size;

  char* base = (char*)d_ws;
  size_t pos = 0;
  auto carve = [&](size_t b) -> void* {
    void* r = base + pos;
    pos += (b + 255) & ~(size_t)255;
    return r;
  };
  int* off_a = (int*)carve((N_MOVIE + 1) * sizeof(int));
  int* off_d = (int*)carve((N_MOVIE + 1) * sizeof(int));
  int* off_w = (int*)carve((N_PERSON + 1) * sizeof(int));
  int* parts = (int*)carve(1024 * sizeof(int));
  int* csr_a = (int*)carve((size_t)E_ACTED * sizeof(int));
  int* csr_d = (int*)carve((size_t)E_DIRECTED * sizeof(int));
  int* csr_w = (int*)carve((size_t)E_WWW * sizeof(int));
  float* xp0 = (float*)carve((size_t)N_PERSON * H * sizeof(float));
  float* xm0 = (float*)carve((size_t)N_MOVIE * H * sizeof(float));
  float* xm1 = (float*)carve((size_t)N_MOVIE * H * sizeof(float));
  float* meanA = (float*)carve((size_t)N_MOVIE * H * sizeof(float));
  float* meanD = (float*)carve((size_t)N_MOVIE * H * sizeof(float));
  float* meanW = (float*)carve((size_t)N_PERSON * H * sizeof(float));
  // transients aliased over meanW (dead until after builds complete)
  int2* pairs = (int2*)meanW;                                     // 25.6 MB max
  int* counts = (int*)((char*)meanW + (((size_t)E_WWW * 8 + 255) & ~(size_t)255));
  int* off_bb = counts + 155648;  // max nbuk*nblk+1 = 782*196+1

  auto build = [&](const int* src, const int* dstp, int E, int N, int* off, int* csr) {
    int nbuk = (N + 255) >> SH;
    int nblk = (E + CH - 1) / CH;
    int n = nbuk * nblk;
    part_count_k<<<nblk, 256, 0, stream>>>(dstp, E, nblk, nbuk, counts);
    int nb = (n + 1023) / 1024;
    scan_block_k<<<nb, 1024, 0, stream>>>(counts, n, off_bb, parts);
    scan_block_k<<<1, 1024, 0, stream>>>(parts, nb, parts, nullptr);
    add_off_k<<<(n + 1 + 1023) / 1024, 1024, 0, stream>>>(off_bb, n, parts, E);
    part_scatter_k<<<nblk, 256, 0, stream>>>(src, dstp, E, nblk, nbuk, off_bb, pairs);
    fine_sort_k<<<nbuk, 256, 0, stream>>>(pairs, E, nblk, nbuk, N, off_bb, off, csr);
  };

  build(acted_src, acted_dst, E_ACTED, N_MOVIE, off_a, csr_a);
  build(directed_src, directed_dst, E_DIRECTED, N_MOVIE, off_d, csr_d);
  build(www_src, www_dst, E_WWW, N_PERSON, off_w, csr_w);

  auto pull = [&](const float* xsrc, const int* off, const int* csr, int n, float* mo) {
    pull_mean_k<<<(n + 3) / 4, 256, 0, stream>>>(xsrc, off, csr, n, mo);
  };

  const float* xp_cur = x_person;
  const float* xm_cur = x_movie;
  float* xm_buf[2] = {xm0, xm1};

  for (int l = 0; l < N_LAYERS; ++l) {
    float* xm_new = xm_buf[l];
    const float* WlA = Wl_acted + l * 64 * 64;
    const float* WrA = Wr_acted + l * 64 * 64;
    const float* WlD = Wl_directed + l * 64 * 64;
    const float* WrD = Wr_directed + l * 64 * 64;
    const float* WlW = Wl_www + l * 64 * 64;
    const float* WrW = Wr_www + l * 64 * 64;
    const float* bA = bl_acted + l * 64;
    const float* bD = bl_directed + l * 64;
    const float* bW = bl_www + l * 64;

    // movie = relu( meanA@WlA^T + meanD@WlD^T + xm@(WrA+WrD)^T + bA + bD )
    pull(xp_cur, off_a, csr_a, N_MOVIE, meanA);
    pull(xp_cur, off_d, csr_d, N_MOVIE, meanD);
    gemm_fused_k<<<(N_MOVIE + 127) / 128, 256, 0, stream>>>(
        N_MOVIE, 3, meanA, meanD, xm_cur, WlA, WlD, WrA, WrD, bA, bD, xm_new, 1);

    // person = relu( meanW@WlW^T + xp@WrW^T + bW ) — dead code in last layer
    if (l + 1 < N_LAYERS) {
      pull(xp_cur, off_w, csr_w, N_PERSON, meanW);
      gemm_fused_k<<<(N_PERSON + 127) / 128, 256, 0, stream>>>(
          N_PERSON, 2, meanW, xp_cur, nullptr, WlW, WrW, nullptr, nullptr, bW, nullptr, xp0, 1);
      xp_cur = xp0;
    }
    xm_cur = xm_new;
  }

  final_k<<<(N_MOVIE + 3) / 4, 256, 0, stream>>>(xm_cur, lin_W, lin_b, out, N_MOVIE);
}

// Round 3
// 796.673 us; speedup vs baseline: 1.7907x; 1.0790x over previous
//
#include <hip/hip_runtime.h>

#define H 64
#define N_PERSON 200000
#define N_MOVIE 100000
#define E_ACTED 1600000
#define E_DIRECTED 200000
#define E_WWW 3200000
#define N_LAYERS 2

#define SH 8          // bucket = dst >> 8 (256 dsts per bucket)
#define CH 16384      // edges per partition block

static __device__ __forceinline__ ushort f2bf(float f) {
  uint u = __float_as_uint(f);
  uint r = (u + 0x7FFFu + ((u >> 16) & 1u)) >> 16;
  return (ushort)r;
}

// ---------------- fp32 -> bf16 cast ----------------

static __global__ __launch_bounds__(256) void cast_bf_k(const float* __restrict__ in,
                                                        ushort* __restrict__ out, int n4) {
  int i = blockIdx.x * 256 + threadIdx.x;
  int stride = gridDim.x * 256;
  for (; i < n4; i += stride) {
    float4 v = ((const float4*)in)[i];
    ushort4 o;
    o.x = f2bf(v.x); o.y = f2bf(v.y); o.z = f2bf(v.z); o.w = f2bf(v.w);
    ((ushort4*)out)[i] = o;
  }
}

// ---------------- scan helpers ----------------

static __global__ __launch_bounds__(1024) void scan_block_k(const int* __restrict__ in, int n,
                                                            int* __restrict__ out,
                                                            int* __restrict__ partials) {
  __shared__ int sm[1024];
  int tid = threadIdx.x;
  int gid = blockIdx.x * 1024 + tid;
  int v = (gid < n) ? in[gid] : 0;
  sm[tid] = v;
  __syncthreads();
  for (int d = 1; d < 1024; d <<= 1) {
    int t = (tid >= d) ? sm[tid - d] : 0;
    __syncthreads();
    if (tid >= d) sm[tid] += t;
    __syncthreads();
  }
  if (gid < n) out[gid] = sm[tid] - v;  // exclusive
  if (tid == 1023 && partials) partials[blockIdx.x] = sm[1023];
}

static __global__ __launch_bounds__(1024) void add_off_k(int* __restrict__ off, int n,
                                                         const int* __restrict__ parts, int total) {
  int gid = blockIdx.x * 1024 + threadIdx.x;
  if (gid < n) off[gid] += parts[gid >> 10];
  else if (gid == n) off[gid] = total;
}

// ---------------- two-level counting sort CSR build ----------------

static __global__ __launch_bounds__(256) void part_count_k(const int* __restrict__ dst, int E,
                                                           int nblk, int nbuk,
                                                           int* __restrict__ counts) {
  __shared__ int hist[800];
  int blk = blockIdx.x, t = threadIdx.x;
  for (int i = t; i < nbuk; i += 256) hist[i] = 0;
  __syncthreads();
  int e0 = blk * CH, e1 = min(e0 + CH, E);
  for (int e = e0 + t; e < e1; e += 256) atomicAdd(&hist[dst[e] >> SH], 1);
  __syncthreads();
  for (int i = t; i < nbuk; i += 256) counts[(size_t)i * nblk + blk] = hist[i];
}

static __global__ __launch_bounds__(256) void part_scatter_k(const int* __restrict__ src,
                                                             const int* __restrict__ dst, int E,
                                                             int nblk, int nbuk,
                                                             const int* __restrict__ off_bb,
                                                             int* __restrict__ pairs) {
  __shared__ int cur[800];
  int blk = blockIdx.x, t = threadIdx.x;
  for (int i = t; i < nbuk; i += 256) cur[i] = off_bb[(size_t)i * nblk + blk];
  __syncthreads();
  int e0 = blk * CH, e1 = min(e0 + CH, E);
  for (int e = e0 + t; e < e1; e += 256) {
    int d = dst[e];
    int pos = atomicAdd(&cur[d >> SH], 1);
    pairs[pos] = ((d & 255) << 24) | src[e];  // src < 2^18
  }
}

static __global__ __launch_bounds__(256) void fine_sort_k(const int* __restrict__ pairs, int E,
                                                          int nblk, int nbuk, int N,
                                                          const int* __restrict__ off_bb,
                                                          int* __restrict__ off,
                                                          int* __restrict__ csr) {
  __shared__ int hist[256];
  __shared__ int sc[256];
  int b = blockIdx.x, t = threadIdx.x;
  int bstart = off_bb[(size_t)b * nblk];
  int bend = off_bb[(size_t)(b + 1) * nblk];  // off_bb[nbuk*nblk] == E
  int base = b << SH;
  hist[t] = 0;
  __syncthreads();
  for (int e = bstart + t; e < bend; e += 256) atomicAdd(&hist[((uint)pairs[e]) >> 24], 1);
  __syncthreads();
  sc[t] = hist[t];
  __syncthreads();
  for (int d = 1; d < 256; d <<= 1) {
    int u = (t >= d) ? sc[t - d] : 0;
    __syncthreads();
    sc[t] += u;
    __syncthreads();
  }
  int excl = sc[t] - hist[t];
  if (base + t < N) off[base + t] = bstart + excl;
  if (b == nbuk - 1 && t == 0) off[N] = E;
  hist[t] = excl;  // reuse as cursor
  __syncthreads();
  for (int e = bstart + t; e < bend; e += 256) {
    int p = pairs[e];
    int pos = bstart + atomicAdd(&hist[((uint)p) >> 24], 1);
    csr[pos] = p & 0x00FFFFFF;
  }
}

// ---------------- pull mean over bf16 source (one wave per dst, 2 edges/iter) ----------------

static __global__ __launch_bounds__(256) void pull_mean_bf_k(const ushort* __restrict__ xsrc,
                                                             const int* __restrict__ off,
                                                             const int* __restrict__ csr,
                                                             int n_dst,
                                                             float* __restrict__ meanout) {
  int wid = (blockIdx.x * 256 + threadIdx.x) >> 6;
  int lane = threadIdx.x & 63;
  if (wid >= n_dst) return;
  int half = lane >> 5;  // 0: even edges, 1: odd edges
  int fl = lane & 31;    // feature pair index (features 2fl, 2fl+1)
  int e0 = off[wid], e1 = off[wid + 1];
  float a0 = 0.f, a1 = 0.f, b0 = 0.f, b1 = 0.f;
  int e = e0;
  for (; e + 4 <= e1; e += 4) {
    int sA = csr[e + half];
    int sB = csr[e + 2 + half];
    uint uA = *(const uint*)(xsrc + (size_t)sA * 64 + fl * 2);
    uint uB = *(const uint*)(xsrc + (size_t)sB * 64 + fl * 2);
    a0 += __uint_as_float(uA << 16);
    a1 += __uint_as_float(uA & 0xFFFF0000u);
    b0 += __uint_as_float(uB << 16);
    b1 += __uint_as_float(uB & 0xFFFF0000u);
  }
  for (; e + 2 <= e1; e += 2) {
    int s = csr[e + half];
    uint u = *(const uint*)(xsrc + (size_t)s * 64 + fl * 2);
    a0 += __uint_as_float(u << 16);
    a1 += __uint_as_float(u & 0xFFFF0000u);
  }
  if (e < e1 && half == 0) {
    int s = csr[e];
    uint u = *(const uint*)(xsrc + (size_t)s * 64 + fl * 2);
    a0 += __uint_as_float(u << 16);
    a1 += __uint_as_float(u & 0xFFFF0000u);
  }
  a0 += b0;
  a1 += b1;
  a0 += __shfl_xor(a0, 32, 64);
  a1 += __shfl_xor(a1, 32, 64);
  if (half == 0) {
    float inv = 1.0f / fmaxf((float)(e1 - e0), 1.0f);
    *(float2*)(meanout + (size_t)wid * 64 + fl * 2) = make_float2(a0 * inv, a1 * inv);
  }
}

// ---- fused fp32 GEMM: C = sum_s A_s @ (W_s [+Wadd])^T + b0 + b1, relu;
//      output: fp32 | bf16 | fused 64->1 projection ----

static __global__ __launch_bounds__(256) void gemm_fused_k(
    int M, int nsrc, const float* __restrict__ A0, const float* __restrict__ A1,
    const float* __restrict__ A2, const float* __restrict__ W0, const float* __restrict__ W1,
    const float* __restrict__ W2, const float* __restrict__ Wadd,
    const float* __restrict__ bias0, const float* __restrict__ bias1,
    float* __restrict__ CoutF, ushort* __restrict__ CoutB, const float* __restrict__ projW,
    const float* __restrict__ projb, float* __restrict__ projOut) {
  __shared__ float At[64 * 132];  // At[k*132 + row]
  __shared__ float Wt[64 * 68];   // Wt[k*68 + j]
  const float* As[3] = {A0, A1, A2};
  const float* Ws[3] = {W0, W1, W2};
  const int t = threadIdx.x;
  const int m0 = blockIdx.x * 128;
  const int tc = t & 15;
  const int tr = t >> 4;
  float acc[8][4];
#pragma unroll
  for (int r = 0; r < 8; ++r)
#pragma unroll
    for (int c = 0; c < 4; ++c) acc[r][c] = 0.f;

  for (int s = 0; s < nsrc; ++s) {
    if (s) __syncthreads();
    const float* W = Ws[s];
    const float* Wa = (s == nsrc - 1) ? Wadd : nullptr;
    for (int i = 0; i < 4; ++i) {
      int f = i * 256 + t;
      int j = f & 63;
      int c4 = f >> 6;
      float4 v = *(const float4*)(W + j * 64 + c4 * 4);
      if (Wa) {
        float4 v2 = *(const float4*)(Wa + j * 64 + c4 * 4);
        v.x += v2.x; v.y += v2.y; v.z += v2.z; v.w += v2.w;
      }
      Wt[(c4 * 4 + 0) * 68 + j] = v.x;
      Wt[(c4 * 4 + 1) * 68 + j] = v.y;
      Wt[(c4 * 4 + 2) * 68 + j] = v.z;
      Wt[(c4 * 4 + 3) * 68 + j] = v.w;
    }
    const float* A = As[s];
    for (int i = 0; i < 8; ++i) {
      int f = i * 256 + t;
      int row = f & 127;
      int c4 = f >> 7;
      int m = m0 + row;
      float4 v = make_float4(0.f, 0.f, 0.f, 0.f);
      if (m < M) v = *(const float4*)(A + (size_t)m * 64 + c4 * 4);
      At[(c4 * 4 + 0) * 132 + row] = v.x;
      At[(c4 * 4 + 1) * 132 + row] = v.y;
      At[(c4 * 4 + 2) * 132 + row] = v.z;
      At[(c4 * 4 + 3) * 132 + row] = v.w;
    }
    __syncthreads();

#pragma unroll 8
    for (int k = 0; k < 64; ++k) {
      float4 w = *(const float4*)(&Wt[k * 68 + tc * 4]);
      float4 a0 = *(const float4*)(&At[k * 132 + tr * 8]);
      float4 a1 = *(const float4*)(&At[k * 132 + tr * 8 + 4]);
      float av[8] = {a0.x, a0.y, a0.z, a0.w, a1.x, a1.y, a1.z, a1.w};
      float wv[4] = {w.x, w.y, w.z, w.w};
#pragma unroll
      for (int r = 0; r < 8; ++r)
#pragma unroll
        for (int c = 0; c < 4; ++c) acc[r][c] = fmaf(av[r], wv[c], acc[r][c]);
    }
  }

  float4 bv = make_float4(0.f, 0.f, 0.f, 0.f);
  if (bias0) {
    float4 b0 = *(const float4*)(bias0 + tc * 4);
    bv.x += b0.x; bv.y += b0.y; bv.z += b0.z; bv.w += b0.w;
  }
  if (bias1) {
    float4 b1 = *(const float4*)(bias1 + tc * 4);
    bv.x += b1.x; bv.y += b1.y; bv.z += b1.z; bv.w += b1.w;
  }

  float4 pw = make_float4(0.f, 0.f, 0.f, 0.f);
  float pb = 0.f;
  if (projOut) {
    pw = *(const float4*)(projW + tc * 4);
    pb = projb[0];
  }

#pragma unroll
  for (int r = 0; r < 8; ++r) {
    int m = m0 + tr * 8 + r;
    if (m < M) {
      float4 o;
      o.x = fmaxf(acc[r][0] + bv.x, 0.f);
      o.y = fmaxf(acc[r][1] + bv.y, 0.f);
      o.z = fmaxf(acc[r][2] + bv.z, 0.f);
      o.w = fmaxf(acc[r][3] + bv.w, 0.f);
      if (projOut) {
        float p = o.x * pw.x + o.y * pw.y + o.z * pw.z + o.w * pw.w;
        p += __shfl_xor(p, 1, 64);
        p += __shfl_xor(p, 2, 64);
        p += __shfl_xor(p, 4, 64);
        p += __shfl_xor(p, 8, 64);
        if (tc == 0) projOut[m] = p + pb;
      } else if (CoutB) {
        ushort4 ob;
        ob.x = f2bf(o.x); ob.y = f2bf(o.y); ob.z = f2bf(o.z); ob.w = f2bf(o.w);
        *(ushort4*)(CoutB + (size_t)m * 64 + tc * 4) = ob;
      } else {
        *(float4*)(CoutF + (size_t)m * 64 + tc * 4) = o;
      }
    }
  }
}

// ---------------- launch ----------------

extern "C" void kernel_launch(void* const* d_in, const int* in_sizes, int n_in, void* d_out,
                              int out_size, void* d_ws, size_t ws_size, hipStream_t stream) {
  const float* x_person = (const float*)d_in[0];
  const float* x_movie = (const float*)d_in[1];
  const int* acted_src = (const int*)d_in[2];
  const int* acted_dst = (const int*)d_in[3];
  const int* directed_src = (const int*)d_in[4];
  const int* directed_dst = (const int*)d_in[5];
  const int* www_src = (const int*)d_in[6];
  const int* www_dst = (const int*)d_in[7];
  const float* Wl_acted = (const float*)d_in[8];
  const float* bl_acted = (const float*)d_in[9];
  const float* Wr_acted = (const float*)d_in[10];
  const float* Wl_directed = (const float*)d_in[11];
  const float* bl_directed = (const float*)d_in[12];
  const float* Wr_directed = (const float*)d_in[13];
  const float* Wl_www = (const float*)d_in[14];
  const float* bl_www = (const float*)d_in[15];
  const float* Wr_www = (const float*)d_in[16];
  const float* lin_W = (const float*)d_in[17];
  const float* lin_b = (const float*)d_in[18];
  float* out = (float*)d_out;
  (void)in_sizes; (void)n_in; (void)out_size; (void)ws_size;

  char* base = (char*)d_ws;
  size_t pos = 0;
  auto carve = [&](size_t b) -> void* {
    void* r = base + pos;
    pos += (b + 255) & ~(size_t)255;
    return r;
  };
  int* off_a = (int*)carve((N_MOVIE + 1) * sizeof(int));
  int* off_d = (int*)carve((N_MOVIE + 1) * sizeof(int));
  int* off_w = (int*)carve((N_PERSON + 1) * sizeof(int));
  int* parts = (int*)carve(1024 * sizeof(int));
  int* csr_a = (int*)carve((size_t)E_ACTED * sizeof(int));
  int* csr_d = (int*)carve((size_t)E_DIRECTED * sizeof(int));
  int* csr_w = (int*)carve((size_t)E_WWW * sizeof(int));
  ushort* xpbf = (ushort*)carve((size_t)N_PERSON * H * sizeof(ushort));   // bf16 x_person
  ushort* xp0bf = (ushort*)carve((size_t)N_PERSON * H * sizeof(ushort));  // bf16 layer-1 person out
  float* xm0 = (float*)carve((size_t)N_MOVIE * H * sizeof(float));
  float* meanA = (float*)carve((size_t)N_MOVIE * H * sizeof(float));
  float* meanD = (float*)carve((size_t)N_MOVIE * H * sizeof(float));
  float* meanW = (float*)carve((size_t)N_PERSON * H * sizeof(float));
  // build transients aliased over meanW (dead until builds complete)
  int* pairs = (int*)meanW;  // 12.8 MB max (packed 4 B/edge)
  int* counts = (int*)((char*)meanW + (((size_t)E_WWW * 4 + 255) & ~(size_t)255));
  int* off_bb = counts + 155648;  // max nbuk*nblk+1 = 782*196+1

  auto build = [&](const int* src, const int* dstp, int E, int N, int* off, int* csr) {
    int nbuk = (N + 255) >> SH;
    int nblk = (E + CH - 1) / CH;
    int n = nbuk * nblk;
    part_count_k<<<nblk, 256, 0, stream>>>(dstp, E, nblk, nbuk, counts);
    int nb = (n + 1023) / 1024;
    scan_block_k<<<nb, 1024, 0, stream>>>(counts, n, off_bb, parts);
    scan_block_k<<<1, 1024, 0, stream>>>(parts, nb, parts, nullptr);
    add_off_k<<<(n + 1 + 1023) / 1024, 1024, 0, stream>>>(off_bb, n, parts, E);
    part_scatter_k<<<nblk, 256, 0, stream>>>(src, dstp, E, nblk, nbuk, off_bb, pairs);
    fine_sort_k<<<nbuk, 256, 0, stream>>>(pairs, E, nblk, nbuk, N, off_bb, off, csr);
  };

  build(acted_src, acted_dst, E_ACTED, N_MOVIE, off_a, csr_a);
  build(directed_src, directed_dst, E_DIRECTED, N_MOVIE, off_d, csr_d);
  build(www_src, www_dst, E_WWW, N_PERSON, off_w, csr_w);

  cast_bf_k<<<4096, 256, 0, stream>>>(x_person, xpbf, N_PERSON * H / 4);

  auto pull = [&](const ushort* xsrc, const int* off, const int* csr, int n, float* mo) {
    pull_mean_bf_k<<<(n + 3) / 4, 256, 0, stream>>>(xsrc, off, csr, n, mo);
  };

  // ---- layer 1 ----
  const float* WlA = Wl_acted, *WrA = Wr_acted, *WlD = Wl_directed, *WrD = Wr_directed;
  const float* WlW = Wl_www, *WrW = Wr_www;
  pull(xpbf, off_a, csr_a, N_MOVIE, meanA);
  pull(xpbf, off_d, csr_d, N_MOVIE, meanD);
  gemm_fused_k<<<(N_MOVIE + 127) / 128, 256, 0, stream>>>(
      N_MOVIE, 3, meanA, meanD, x_movie, WlA, WlD, WrA, WrD, bl_acted, bl_directed,
      xm0, nullptr, nullptr, nullptr, nullptr);
  pull(xpbf, off_w, csr_w, N_PERSON, meanW);
  gemm_fused_k<<<(N_PERSON + 127) / 128, 256, 0, stream>>>(
      N_PERSON, 2, meanW, x_person, nullptr, WlW, WrW, nullptr, nullptr, bl_www, nullptr,
      nullptr, xp0bf, nullptr, nullptr, nullptr);

  // ---- layer 2 (person conv is dead code; movie conv fused with final projection) ----
  pull(xp0bf, off_a, csr_a, N_MOVIE, meanA);
  pull(xp0bf, off_d, csr_d, N_MOVIE, meanD);
  gemm_fused_k<<<(N_MOVIE + 127) / 128, 256, 0, stream>>>(
      N_MOVIE, 3, meanA, meanD, xm0, Wl_acted + 4096, Wl_directed + 4096, Wr_acted + 4096,
      Wr_directed + 4096, bl_acted + 64, bl_directed + 64,
      nullptr, nullptr, lin_W, lin_b, out);
}

// Round 4
// 545.741 us; speedup vs baseline: 2.6141x; 1.4598x over previous
//
#include <hip/hip_runtime.h>

#define H 64
#define N_PERSON 200000
#define N_MOVIE 100000
#define E_ACTED 1600000
#define E_DIRECTED 200000
#define E_WWW 3200000
#define E_TOTAL (E_ACTED + E_DIRECTED + E_WWW)

#define SH 8          // bucket = dst >> 8 (256 dsts per bucket)
#define CH 16384      // edges per partition block

static __device__ __forceinline__ ushort f2bf(float f) {
  uint u = __float_as_uint(f);
  uint r = (u + 0x7FFFu + ((u >> 16) & 1u)) >> 16;
  return (ushort)r;
}
static __device__ __forceinline__ float bflo(uint u) { return __uint_as_float(u << 16); }
static __device__ __forceinline__ float bfhi(uint u) { return __uint_as_float(u & 0xFFFF0000u); }

// ---------------- relation descriptor ----------------

struct RelP {
  const int* src; const int* dst; int* off;
  int E, N, nblk, nbuk, blkbase, bukbase, cbase, ebase;
};

// ---------------- fp32 -> bf16 cast (two tensors, one launch) ----------------

static __global__ __launch_bounds__(256) void cast_all_k(const float* __restrict__ i0,
                                                         ushort* __restrict__ o0, int n0,
                                                         const float* __restrict__ i1,
                                                         ushort* __restrict__ o1, int n1) {
  int i = blockIdx.x * 256 + threadIdx.x;
  int stride = gridDim.x * 256;
  int nt = n0 + n1;
  for (; i < nt; i += stride) {
    const float4* in; ushort4* out; int idx;
    if (i < n0) { in = (const float4*)i0; out = (ushort4*)o0; idx = i; }
    else { in = (const float4*)i1; out = (ushort4*)o1; idx = i - n0; }
    float4 v = in[idx];
    ushort4 o;
    o.x = f2bf(v.x); o.y = f2bf(v.y); o.z = f2bf(v.z); o.w = f2bf(v.w);
    out[idx] = o;
  }
}

// ---------------- scan helpers ----------------

static __global__ __launch_bounds__(1024) void scan_block_k(const int* __restrict__ in, int n,
                                                            int* __restrict__ out,
                                                            int* __restrict__ partials) {
  __shared__ int sm[1024];
  int tid = threadIdx.x;
  int gid = blockIdx.x * 1024 + tid;
  int v = (gid < n) ? in[gid] : 0;
  sm[tid] = v;
  __syncthreads();
  for (int d = 1; d < 1024; d <<= 1) {
    int t = (tid >= d) ? sm[tid - d] : 0;
    __syncthreads();
    if (tid >= d) sm[tid] += t;
    __syncthreads();
  }
  if (gid < n) out[gid] = sm[tid] - v;  // exclusive
  if (tid == 1023 && partials) partials[blockIdx.x] = sm[1023];
}

static __global__ __launch_bounds__(1024) void add_off_k(int* __restrict__ off, int n,
                                                         const int* __restrict__ parts, int total) {
  int gid = blockIdx.x * 1024 + threadIdx.x;
  if (gid < n) off[gid] += parts[gid >> 10];
  else if (gid == n) off[gid] = total;
}

// ---------------- two-level counting sort, all relations fused ----------------

static __global__ __launch_bounds__(256) void part_count_all_k(RelP a, RelP b, RelP c,
                                                               int* __restrict__ counts) {
  __shared__ int hist[800];
  int blk = blockIdx.x, t = threadIdx.x;
  RelP r = (blk >= c.blkbase) ? c : (blk >= b.blkbase) ? b : a;
  int lb = blk - r.blkbase;
  for (int i = t; i < r.nbuk; i += 256) hist[i] = 0;
  __syncthreads();
  int e0 = lb * CH, e1 = min(e0 + CH, r.E);
  for (int e = e0 + t; e < e1; e += 256) atomicAdd(&hist[r.dst[e] >> SH], 1);
  __syncthreads();
  for (int i = t; i < r.nbuk; i += 256) counts[r.cbase + i * r.nblk + lb] = hist[i];
}

static __global__ __launch_bounds__(256) void part_scatter_all_k(RelP a, RelP b, RelP c,
                                                                 const int* __restrict__ off_bb,
                                                                 int* __restrict__ pairs) {
  __shared__ int cur[800];
  int blk = blockIdx.x, t = threadIdx.x;
  RelP r = (blk >= c.blkbase) ? c : (blk >= b.blkbase) ? b : a;
  int lb = blk - r.blkbase;
  for (int i = t; i < r.nbuk; i += 256) cur[i] = off_bb[r.cbase + i * r.nblk + lb];
  __syncthreads();
  int e0 = lb * CH, e1 = min(e0 + CH, r.E);
  for (int e = e0 + t; e < e1; e += 256) {
    int d = r.dst[e];
    int pos = atomicAdd(&cur[d >> SH], 1);
    pairs[pos] = ((d & 255) << 24) | r.src[e];  // src < 2^18
  }
}

static __global__ __launch_bounds__(256) void fine_sort_all_k(RelP a, RelP b, RelP c,
                                                              const int* __restrict__ off_bb,
                                                              const int* __restrict__ pairs,
                                                              int* __restrict__ csr) {
  __shared__ int hist[256];
  __shared__ int sc[256];
  int bb = blockIdx.x, t = threadIdx.x;
  RelP r = (bb >= c.bukbase) ? c : (bb >= b.bukbase) ? b : a;
  int bkt = bb - r.bukbase;
  int bstart = off_bb[r.cbase + bkt * r.nblk];
  int bend = (bkt + 1 < r.nbuk) ? off_bb[r.cbase + (bkt + 1) * r.nblk] : (r.ebase + r.E);
  int base = bkt << SH;
  hist[t] = 0;
  __syncthreads();
  for (int e = bstart + t; e < bend; e += 256) atomicAdd(&hist[((uint)pairs[e]) >> 24], 1);
  __syncthreads();
  sc[t] = hist[t];
  __syncthreads();
  for (int d = 1; d < 256; d <<= 1) {
    int u = (t >= d) ? sc[t - d] : 0;
    __syncthreads();
    sc[t] += u;
    __syncthreads();
  }
  int excl = sc[t] - hist[t];
  if (base + t < r.N) r.off[base + t] = bstart + excl;  // global edge index
  if (bkt == r.nbuk - 1 && t == 0) r.off[r.N] = r.ebase + r.E;
  hist[t] = excl;  // reuse as cursor
  __syncthreads();
  for (int e = bstart + t; e < bend; e += 256) {
    int p = pairs[e];
    int pos = bstart + atomicAdd(&hist[((uint)p) >> 24], 1);
    csr[pos] = p & 0x00FFFFFF;
  }
}

// ---------------- multi-task pull mean (bf16 in, bf16 out), 8 edges in flight ----------------

struct PullT { const ushort* xsrc; const int* off; ushort* mean; int n; int blkbase; };

static __global__ __launch_bounds__(256) void pull_all_k(PullT t0, PullT t1, PullT t2,
                                                         const int* __restrict__ csr) {
  int blk = blockIdx.x;
  PullT tk;
  if (t2.n > 0 && blk >= t2.blkbase) tk = t2;
  else if (blk >= t1.blkbase) tk = t1;
  else tk = t0;
  int wid = (blk - tk.blkbase) * 4 + (threadIdx.x >> 6);
  int lane = threadIdx.x & 63;
  if (wid >= tk.n) return;
  int half = lane >> 5;  // 0: even edges, 1: odd edges
  int fl = lane & 31;    // feature pair (2fl, 2fl+1)
  int e0 = tk.off[wid], e1 = tk.off[wid + 1];
  const ushort* xs = tk.xsrc;
  float x0 = 0.f, x1 = 0.f, y0 = 0.f, y1 = 0.f, z0 = 0.f, z1 = 0.f, w0 = 0.f, w1 = 0.f;
  int e = e0;
  for (; e + 8 <= e1; e += 8) {
    int sA = csr[e + half], sB = csr[e + 2 + half], sC = csr[e + 4 + half], sD = csr[e + 6 + half];
    uint ua = *(const uint*)(xs + (size_t)sA * 64 + fl * 2);
    uint ub = *(const uint*)(xs + (size_t)sB * 64 + fl * 2);
    uint uc = *(const uint*)(xs + (size_t)sC * 64 + fl * 2);
    uint ud = *(const uint*)(xs + (size_t)sD * 64 + fl * 2);
    x0 += bflo(ua); x1 += bfhi(ua);
    y0 += bflo(ub); y1 += bfhi(ub);
    z0 += bflo(uc); z1 += bfhi(uc);
    w0 += bflo(ud); w1 += bfhi(ud);
  }
  for (; e + 2 <= e1; e += 2) {
    int s = csr[e + half];
    uint u = *(const uint*)(xs + (size_t)s * 64 + fl * 2);
    x0 += bflo(u); x1 += bfhi(u);
  }
  if (e < e1 && half == 0) {
    int s = csr[e];
    uint u = *(const uint*)(xs + (size_t)s * 64 + fl * 2);
    x0 += bflo(u); x1 += bfhi(u);
  }
  x0 += y0 + z0 + w0;
  x1 += y1 + z1 + w1;
  x0 += __shfl_xor(x0, 32, 64);
  x1 += __shfl_xor(x1, 32, 64);
  if (half == 0) {
    float inv = 1.0f / fmaxf((float)(e1 - e0), 1.0f);
    ushort2 o;
    o.x = f2bf(x0 * inv);
    o.y = f2bf(x1 * inv);
    *(ushort2*)(tk.mean + (size_t)wid * 64 + fl * 2) = o;
  }
}

// ---- fused GEMM (bf16 A, fp32 W/acc): C = sum_s A_s @ (W_s [+Wadd])^T + b0 + b1, relu;
//      output bf16, or fused 64->1 projection. Two tasks per launch. ----

struct GemmT {
  const ushort *A0, *A1, *A2;
  const float *W0, *W1, *W2, *Wadd, *b0, *b1;
  ushort* outB;
  const float *projW, *projb;
  float* projOut;
  int M, nsrc, blkbase;
};

static __global__ __launch_bounds__(256) void gemm_all_k(GemmT g0, GemmT g1) {
  GemmT g = (g1.M > 0 && (int)blockIdx.x >= g1.blkbase) ? g1 : g0;
  __shared__ float At[64 * 132];  // At[k*132 + row]
  __shared__ float Wt[64 * 68];   // Wt[k*68 + j]
  const ushort* As[3] = {g.A0, g.A1, g.A2};
  const float* Ws[3] = {g.W0, g.W1, g.W2};
  const int t = threadIdx.x;
  const int m0 = ((int)blockIdx.x - g.blkbase) * 128;
  const int tc = t & 15;
  const int tr = t >> 4;
  float acc[8][4];
#pragma unroll
  for (int r = 0; r < 8; ++r)
#pragma unroll
    for (int c = 0; c < 4; ++c) acc[r][c] = 0.f;

  for (int s = 0; s < g.nsrc; ++s) {
    if (s) __syncthreads();
    const float* W = Ws[s];
    const float* Wa = (s == g.nsrc - 1) ? g.Wadd : nullptr;
    for (int i = 0; i < 4; ++i) {
      int f = i * 256 + t;
      int j = f & 63;
      int c4 = f >> 6;
      float4 v = *(const float4*)(W + j * 64 + c4 * 4);
      if (Wa) {
        float4 v2 = *(const float4*)(Wa + j * 64 + c4 * 4);
        v.x += v2.x; v.y += v2.y; v.z += v2.z; v.w += v2.w;
      }
      Wt[(c4 * 4 + 0) * 68 + j] = v.x;
      Wt[(c4 * 4 + 1) * 68 + j] = v.y;
      Wt[(c4 * 4 + 2) * 68 + j] = v.z;
      Wt[(c4 * 4 + 3) * 68 + j] = v.w;
    }
    const ushort* A = As[s];
    for (int i = 0; i < 4; ++i) {
      int f = i * 256 + t;   // 1024 chunks of 8 bf16
      int row = f & 127;
      int c8 = f >> 7;       // [0,8)
      int m = m0 + row;
      uint4 u = make_uint4(0, 0, 0, 0);
      if (m < g.M) u = *(const uint4*)(A + (size_t)m * 64 + c8 * 8);
      At[(c8 * 8 + 0) * 132 + row] = bflo(u.x);
      At[(c8 * 8 + 1) * 132 + row] = bfhi(u.x);
      At[(c8 * 8 + 2) * 132 + row] = bflo(u.y);
      At[(c8 * 8 + 3) * 132 + row] = bfhi(u.y);
      At[(c8 * 8 + 4) * 132 + row] = bflo(u.z);
      At[(c8 * 8 + 5) * 132 + row] = bfhi(u.z);
      At[(c8 * 8 + 6) * 132 + row] = bflo(u.w);
      At[(c8 * 8 + 7) * 132 + row] = bfhi(u.w);
    }
    __syncthreads();

#pragma unroll 8
    for (int k = 0; k < 64; ++k) {
      float4 w = *(const float4*)(&Wt[k * 68 + tc * 4]);
      float4 a0 = *(const float4*)(&At[k * 132 + tr * 8]);
      float4 a1 = *(const float4*)(&At[k * 132 + tr * 8 + 4]);
      float av[8] = {a0.x, a0.y, a0.z, a0.w, a1.x, a1.y, a1.z, a1.w};
      float wv[4] = {w.x, w.y, w.z, w.w};
#pragma unroll
      for (int r = 0; r < 8; ++r)
#pragma unroll
        for (int c = 0; c < 4; ++c) acc[r][c] = fmaf(av[r], wv[c], acc[r][c]);
    }
  }

  float4 bv = make_float4(0.f, 0.f, 0.f, 0.f);
  if (g.b0) {
    float4 b0 = *(const float4*)(g.b0 + tc * 4);
    bv.x += b0.x; bv.y += b0.y; bv.z += b0.z; bv.w += b0.w;
  }
  if (g.b1) {
    float4 b1 = *(const float4*)(g.b1 + tc * 4);
    bv.x += b1.x; bv.y += b1.y; bv.z += b1.z; bv.w += b1.w;
  }

  float4 pw = make_float4(0.f, 0.f, 0.f, 0.f);
  float pb = 0.f;
  if (g.projOut) {
    pw = *(const float4*)(g.projW + tc * 4);
    pb = g.projb[0];
  }

#pragma unroll
  for (int r = 0; r < 8; ++r) {
    int m = m0 + tr * 8 + r;
    if (m < g.M) {
      float4 o;
      o.x = fmaxf(acc[r][0] + bv.x, 0.f);
      o.y = fmaxf(acc[r][1] + bv.y, 0.f);
      o.z = fmaxf(acc[r][2] + bv.z, 0.f);
      o.w = fmaxf(acc[r][3] + bv.w, 0.f);
      if (g.projOut) {
        float p = o.x * pw.x + o.y * pw.y + o.z * pw.z + o.w * pw.w;
        p += __shfl_xor(p, 1, 64);
        p += __shfl_xor(p, 2, 64);
        p += __shfl_xor(p, 4, 64);
        p += __shfl_xor(p, 8, 64);
        if (tc == 0) g.projOut[m] = p + pb;
      } else {
        ushort4 ob;
        ob.x = f2bf(o.x); ob.y = f2bf(o.y); ob.z = f2bf(o.z); ob.w = f2bf(o.w);
        *(ushort4*)(g.outB + (size_t)m * 64 + tc * 4) = ob;
      }
    }
  }
}

// ---------------- launch ----------------

extern "C" void kernel_launch(void* const* d_in, const int* in_sizes, int n_in, void* d_out,
                              int out_size, void* d_ws, size_t ws_size, hipStream_t stream) {
  const float* x_person = (const float*)d_in[0];
  const float* x_movie = (const float*)d_in[1];
  const int* acted_src = (const int*)d_in[2];
  const int* acted_dst = (const int*)d_in[3];
  const int* directed_src = (const int*)d_in[4];
  const int* directed_dst = (const int*)d_in[5];
  const int* www_src = (const int*)d_in[6];
  const int* www_dst = (const int*)d_in[7];
  const float* Wl_acted = (const float*)d_in[8];
  const float* bl_acted = (const float*)d_in[9];
  const float* Wr_acted = (const float*)d_in[10];
  const float* Wl_directed = (const float*)d_in[11];
  const float* bl_directed = (const float*)d_in[12];
  const float* Wr_directed = (const float*)d_in[13];
  const float* Wl_www = (const float*)d_in[14];
  const float* bl_www = (const float*)d_in[15];
  const float* Wr_www = (const float*)d_in[16];
  const float* lin_W = (const float*)d_in[17];
  const float* lin_b = (const float*)d_in[18];
  float* out = (float*)d_out;
  (void)in_sizes; (void)n_in; (void)out_size; (void)ws_size;

  char* base = (char*)d_ws;
  size_t pos = 0;
  auto carve = [&](size_t b) -> void* {
    void* r = base + pos;
    pos += (b + 255) & ~(size_t)255;
    return r;
  };
  int* off_a = (int*)carve((N_MOVIE + 1) * sizeof(int));
  int* off_d = (int*)carve((N_MOVIE + 1) * sizeof(int));
  int* off_w = (int*)carve((N_PERSON + 1) * sizeof(int));
  int* parts = (int*)carve(1024 * sizeof(int));
  int* csr_all = (int*)carve((size_t)E_TOTAL * sizeof(int));
  int* pairs = (int*)carve((size_t)E_TOTAL * sizeof(int));
  ushort* xpbf = (ushort*)carve((size_t)N_PERSON * H * sizeof(ushort));
  ushort* xmbf = (ushort*)carve((size_t)N_MOVIE * H * sizeof(ushort));
  ushort* xp0bf = (ushort*)carve((size_t)N_PERSON * H * sizeof(ushort));
  ushort* xm0bf = (ushort*)carve((size_t)N_MOVIE * H * sizeof(ushort));
  ushort* meanAbf = (ushort*)carve((size_t)N_MOVIE * H * sizeof(ushort));
  ushort* meanDbf = (ushort*)carve((size_t)N_MOVIE * H * sizeof(ushort));
  ushort* meanWbf = (ushort*)carve((size_t)N_PERSON * H * sizeof(ushort));

  // relation descriptors (A=acted, D=directed, W=www), contiguous in counts/edges
  RelP rA, rD, rW;
  rA.src = acted_src;  rA.dst = acted_dst;  rA.off = off_a;
  rA.E = E_ACTED;      rA.N = N_MOVIE;
  rA.nblk = (E_ACTED + CH - 1) / CH;      rA.nbuk = (N_MOVIE + 255) >> SH;
  rD.src = directed_src; rD.dst = directed_dst; rD.off = off_d;
  rD.E = E_DIRECTED;     rD.N = N_MOVIE;
  rD.nblk = (E_DIRECTED + CH - 1) / CH;   rD.nbuk = (N_MOVIE + 255) >> SH;
  rW.src = www_src;    rW.dst = www_dst;  rW.off = off_w;
  rW.E = E_WWW;        rW.N = N_PERSON;
  rW.nblk = (E_WWW + CH - 1) / CH;        rW.nbuk = (N_PERSON + 255) >> SH;
  rA.blkbase = 0;                 rD.blkbase = rA.nblk;           rW.blkbase = rA.nblk + rD.nblk;
  rA.bukbase = 0;                 rD.bukbase = rA.nbuk;           rW.bukbase = rA.nbuk + rD.nbuk;
  rA.cbase = 0;                   rD.cbase = rA.nbuk * rA.nblk;
  rW.cbase = rD.cbase + rD.nbuk * rD.nblk;
  rA.ebase = 0;                   rD.ebase = E_ACTED;             rW.ebase = E_ACTED + E_DIRECTED;
  const int n_total = rW.cbase + rW.nbuk * rW.nblk;
  const int nblk_total = rW.blkbase + rW.nblk;
  const int nbuk_total = rW.bukbase + rW.nbuk;

  int* counts = (int*)carve((size_t)n_total * sizeof(int));
  int* off_bb = (int*)carve((size_t)(n_total + 1) * sizeof(int));

  // ---- CSR build (all relations in each launch) ----
  part_count_all_k<<<nblk_total, 256, 0, stream>>>(rA, rD, rW, counts);
  int nb = (n_total + 1023) / 1024;
  scan_block_k<<<nb, 1024, 0, stream>>>(counts, n_total, off_bb, parts);
  scan_block_k<<<1, 1024, 0, stream>>>(parts, nb, parts, nullptr);
  add_off_k<<<(n_total + 1 + 1023) / 1024, 1024, 0, stream>>>(off_bb, n_total, parts, E_TOTAL);
  part_scatter_all_k<<<nblk_total, 256, 0, stream>>>(rA, rD, rW, off_bb, pairs);
  fine_sort_all_k<<<nbuk_total, 256, 0, stream>>>(rA, rD, rW, off_bb, pairs, csr_all);

  // ---- bf16 casts ----
  cast_all_k<<<2048, 256, 0, stream>>>(x_person, xpbf, N_PERSON * H / 4, x_movie, xmbf,
                                       N_MOVIE * H / 4);

  const int nbA = (N_MOVIE + 3) / 4, nbD = (N_MOVIE + 3) / 4, nbW = (N_PERSON + 3) / 4;
  const int gmM = (N_MOVIE + 127) / 128, gmP = (N_PERSON + 127) / 128;

  // ---- layer 1 pulls: acted, directed, www from xpbf ----
  {
    PullT pA = {xpbf, off_a, meanAbf, N_MOVIE, 0};
    PullT pD = {xpbf, off_d, meanDbf, N_MOVIE, nbA};
    PullT pW = {xpbf, off_w, meanWbf, N_PERSON, nbA + nbD};
    pull_all_k<<<nbA + nbD + nbW, 256, 0, stream>>>(pA, pD, pW, csr_all);
  }
  // ---- layer 1 GEMMs: movie (3 srcs) + person (2 srcs), one launch ----
  {
    GemmT gM = {meanAbf, meanDbf, xmbf,
                Wl_acted, Wl_directed, Wr_acted, Wr_directed, bl_acted, bl_directed,
                xm0bf, nullptr, nullptr, nullptr, N_MOVIE, 3, 0};
    GemmT gP = {meanWbf, xpbf, nullptr,
                Wl_www, Wr_www, nullptr, nullptr, bl_www, nullptr,
                xp0bf, nullptr, nullptr, nullptr, N_PERSON, 2, gmM};
    gemm_all_k<<<gmM + gmP, 256, 0, stream>>>(gM, gP);
  }
  // ---- layer 2 pulls: acted, directed from xp0bf ----
  {
    PullT pA = {xp0bf, off_a, meanAbf, N_MOVIE, 0};
    PullT pD = {xp0bf, off_d, meanDbf, N_MOVIE, nbA};
    PullT pZ = {nullptr, nullptr, nullptr, 0, 0};
    pull_all_k<<<nbA + nbD, 256, 0, stream>>>(pA, pD, pZ, csr_all);
  }
  // ---- layer 2 movie GEMM with fused final projection ----
  {
    GemmT gM = {meanAbf, meanDbf, xm0bf,
                Wl_acted + 4096, Wl_directed + 4096, Wr_acted + 4096, Wr_directed + 4096,
                bl_acted + 64, bl_directed + 64,
                nullptr, lin_W, lin_b, out, N_MOVIE, 3, 0};
    GemmT gZ = {nullptr, nullptr, nullptr, nullptr, nullptr, nullptr, nullptr, nullptr, nullptr,
                nullptr, nullptr, nullptr, nullptr, 0, 0, 0};
    gemm_all_k<<<gmM, 256, 0, stream>>>(gM, gZ);
  }
}

// Round 5
// 521.255 us; speedup vs baseline: 2.7369x; 1.0470x over previous
//
#include <hip/hip_runtime.h>

#define H 64
#define N_PERSON 200000
#define N_MOVIE 100000
#define E_ACTED 1600000
#define E_DIRECTED 200000
#define E_WWW 3200000
#define E_TOTAL (E_ACTED + E_DIRECTED + E_WWW)

#define SH 8          // bucket = dst >> 8 (256 dsts per bucket)
#define CH 16384      // edges per partition block

static __device__ __forceinline__ ushort f2bf(float f) {
  uint u = __float_as_uint(f);
  uint r = (u + 0x7FFFu + ((u >> 16) & 1u)) >> 16;
  return (ushort)r;
}
static __device__ __forceinline__ float bflo(uint u) { return __uint_as_float(u << 16); }
static __device__ __forceinline__ float bfhi(uint u) { return __uint_as_float(u & 0xFFFF0000u); }
static __device__ __forceinline__ uint packbf(float lo, float hi) {
  return (uint)f2bf(lo) | ((uint)f2bf(hi) << 16);
}

// ---------------- relation descriptor ----------------

struct RelP {
  const int* src; const int* dst; int* off;
  int E, N, nblk, nbuk, blkbase, bukbase, cbase, ebase;
};

// ---------------- fp32 -> bf16 cast (two tensors, one launch) ----------------

static __global__ __launch_bounds__(256) void cast_all_k(const float* __restrict__ i0,
                                                         ushort* __restrict__ o0, int n0,
                                                         const float* __restrict__ i1,
                                                         ushort* __restrict__ o1, int n1) {
  int i = blockIdx.x * 256 + threadIdx.x;
  int stride = gridDim.x * 256;
  int nt = n0 + n1;
  for (; i < nt; i += stride) {
    const float4* in; ushort4* out; int idx;
    if (i < n0) { in = (const float4*)i0; out = (ushort4*)o0; idx = i; }
    else { in = (const float4*)i1; out = (ushort4*)o1; idx = i - n0; }
    float4 v = in[idx];
    ushort4 o;
    o.x = f2bf(v.x); o.y = f2bf(v.y); o.z = f2bf(v.z); o.w = f2bf(v.w);
    out[idx] = o;
  }
}

// ---------------- scan helpers ----------------

static __global__ __launch_bounds__(1024) void scan_block_k(const int* __restrict__ in, int n,
                                                            int* __restrict__ out,
                                                            int* __restrict__ partials) {
  __shared__ int sm[1024];
  int tid = threadIdx.x;
  int gid = blockIdx.x * 1024 + tid;
  int v = (gid < n) ? in[gid] : 0;
  sm[tid] = v;
  __syncthreads();
  for (int d = 1; d < 1024; d <<= 1) {
    int t = (tid >= d) ? sm[tid - d] : 0;
    __syncthreads();
    if (tid >= d) sm[tid] += t;
    __syncthreads();
  }
  if (gid < n) out[gid] = sm[tid] - v;  // exclusive
  if (tid == 1023 && partials) partials[blockIdx.x] = sm[1023];
}

static __global__ __launch_bounds__(1024) void add_off_k(int* __restrict__ off, int n,
                                                         const int* __restrict__ parts, int total) {
  int gid = blockIdx.x * 1024 + threadIdx.x;
  if (gid < n) off[gid] += parts[gid >> 10];
  else if (gid == n) off[gid] = total;
}

// ---------------- two-level counting sort, all relations fused ----------------

static __global__ __launch_bounds__(256) void part_count_all_k(RelP a, RelP b, RelP c,
                                                               int* __restrict__ counts) {
  __shared__ int hist[800];
  int blk = blockIdx.x, t = threadIdx.x;
  RelP r = (blk >= c.blkbase) ? c : (blk >= b.blkbase) ? b : a;
  int lb = blk - r.blkbase;
  for (int i = t; i < r.nbuk; i += 256) hist[i] = 0;
  __syncthreads();
  int e0 = lb * CH, e1 = min(e0 + CH, r.E);
  for (int e = e0 + t; e < e1; e += 256) atomicAdd(&hist[r.dst[e] >> SH], 1);
  __syncthreads();
  for (int i = t; i < r.nbuk; i += 256) counts[r.cbase + i * r.nblk + lb] = hist[i];
}

static __global__ __launch_bounds__(256) void part_scatter_all_k(RelP a, RelP b, RelP c,
                                                                 const int* __restrict__ off_bb,
                                                                 int* __restrict__ pairs) {
  __shared__ int cur[800];
  int blk = blockIdx.x, t = threadIdx.x;
  RelP r = (blk >= c.blkbase) ? c : (blk >= b.blkbase) ? b : a;
  int lb = blk - r.blkbase;
  for (int i = t; i < r.nbuk; i += 256) cur[i] = off_bb[r.cbase + i * r.nblk + lb];
  __syncthreads();
  int e0 = lb * CH, e1 = min(e0 + CH, r.E);
  for (int e = e0 + t; e < e1; e += 256) {
    int d = r.dst[e];
    int pos = atomicAdd(&cur[d >> SH], 1);
    pairs[pos] = ((d & 255) << 24) | r.src[e];  // src < 2^18
  }
}

static __global__ __launch_bounds__(256) void fine_sort_all_k(RelP a, RelP b, RelP c,
                                                              const int* __restrict__ off_bb,
                                                              const int* __restrict__ pairs,
                                                              int* __restrict__ csr) {
  __shared__ int hist[256];
  __shared__ int sc[256];
  int bb = blockIdx.x, t = threadIdx.x;
  RelP r = (bb >= c.bukbase) ? c : (bb >= b.bukbase) ? b : a;
  int bkt = bb - r.bukbase;
  int bstart = off_bb[r.cbase + bkt * r.nblk];
  int bend = (bkt + 1 < r.nbuk) ? off_bb[r.cbase + (bkt + 1) * r.nblk] : (r.ebase + r.E);
  int base = bkt << SH;
  hist[t] = 0;
  __syncthreads();
  for (int e = bstart + t; e < bend; e += 256) atomicAdd(&hist[((uint)pairs[e]) >> 24], 1);
  __syncthreads();
  sc[t] = hist[t];
  __syncthreads();
  for (int d = 1; d < 256; d <<= 1) {
    int u = (t >= d) ? sc[t - d] : 0;
    __syncthreads();
    sc[t] += u;
    __syncthreads();
  }
  int excl = sc[t] - hist[t];
  if (base + t < r.N) r.off[base + t] = bstart + excl;  // global edge index
  if (bkt == r.nbuk - 1 && t == 0) r.off[r.N] = r.ebase + r.E;
  hist[t] = excl;  // reuse as cursor
  __syncthreads();
  for (int e = bstart + t; e < bend; e += 256) {
    int p = pairs[e];
    int pos = bstart + atomicAdd(&hist[((uint)p) >> 24], 1);
    csr[pos] = p & 0x00FFFFFF;
  }
}

// ---------------- multi-task pull mean (bf16 in, bf16 out) ----------------
// One wave per dst. lane = (eo = lane>>3 edge-octet, fo = lane&7 feature-octet).
// Per 8 edges: 1 dwordx4 gather (full 128B row per 8-lane group).
// csr indices block-loaded coalesced then distributed via shfl.

struct PullT { const ushort* xsrc; const int* off; ushort* mean; int n; int blkbase; };

static __global__ __launch_bounds__(256) void pull_all_k(PullT t0, PullT t1, PullT t2,
                                                         const int* __restrict__ csr) {
  int blk = blockIdx.x;
  PullT tk;
  if (t2.n > 0 && blk >= t2.blkbase) tk = t2;
  else if (blk >= t1.blkbase) tk = t1;
  else tk = t0;
  int wid = (blk - tk.blkbase) * 4 + (threadIdx.x >> 6);
  int lane = threadIdx.x & 63;
  if (wid >= tk.n) return;
  const int eo = lane >> 3;  // edge within batch of 8
  const int fo = lane & 7;   // feature octet
  int e0 = tk.off[wid], e1 = tk.off[wid + 1];
  const ushort* __restrict__ xrow = tk.xsrc + fo * 8;

  float acc[8];
#pragma unroll
  for (int j = 0; j < 8; ++j) acc[j] = 0.f;

  for (int ebase = e0; ebase < e1; ebase += 64) {
    int nv = min(64, e1 - ebase);
    int v = (lane < nv) ? csr[ebase + lane] : 0;
    int b8 = 0;
    // paired batches: 16 edges, 2 gathers in flight
    for (; b8 + 16 <= nv; b8 += 16) {
      int s0 = __shfl(v, b8 + eo, 64);
      int s1 = __shfl(v, b8 + 8 + eo, 64);
      uint4 u0 = *(const uint4*)(xrow + (size_t)s0 * 64);
      uint4 u1 = *(const uint4*)(xrow + (size_t)s1 * 64);
      acc[0] += bflo(u0.x); acc[1] += bfhi(u0.x);
      acc[2] += bflo(u0.y); acc[3] += bfhi(u0.y);
      acc[4] += bflo(u0.z); acc[5] += bfhi(u0.z);
      acc[6] += bflo(u0.w); acc[7] += bfhi(u0.w);
      acc[0] += bflo(u1.x); acc[1] += bfhi(u1.x);
      acc[2] += bflo(u1.y); acc[3] += bfhi(u1.y);
      acc[4] += bflo(u1.z); acc[5] += bfhi(u1.z);
      acc[6] += bflo(u1.w); acc[7] += bfhi(u1.w);
    }
    // remaining 1-2 (possibly partial) batches
    for (; b8 < nv; b8 += 8) {
      int idx = b8 + eo;
      int s = __shfl(v, idx < 63 ? idx : 63, 64);
      if (idx < nv) {
        uint4 u = *(const uint4*)(xrow + (size_t)s * 64);
        acc[0] += bflo(u.x); acc[1] += bfhi(u.x);
        acc[2] += bflo(u.y); acc[3] += bfhi(u.y);
        acc[4] += bflo(u.z); acc[5] += bfhi(u.z);
        acc[6] += bflo(u.w); acc[7] += bfhi(u.w);
      }
    }
  }

  // reduce across the 8 edge-octet groups (stride 8, 16, 32)
#pragma unroll
  for (int j = 0; j < 8; ++j) {
    acc[j] += __shfl_xor(acc[j], 8, 64);
    acc[j] += __shfl_xor(acc[j], 16, 64);
    acc[j] += __shfl_xor(acc[j], 32, 64);
  }

  if (eo == 0) {
    float inv = 1.0f / fmaxf((float)(e1 - e0), 1.0f);
    uint4 o;
    o.x = packbf(acc[0] * inv, acc[1] * inv);
    o.y = packbf(acc[2] * inv, acc[3] * inv);
    o.z = packbf(acc[4] * inv, acc[5] * inv);
    o.w = packbf(acc[6] * inv, acc[7] * inv);
    *(uint4*)(tk.mean + (size_t)wid * 64 + fo * 8) = o;
  }
}

// ---- fused GEMM (bf16 A, fp32 W/acc): C = sum_s A_s @ (W_s [+Wadd])^T + b0 + b1, relu;
//      output bf16, or fused 64->1 projection. Two tasks per launch. ----

struct GemmT {
  const ushort *A0, *A1, *A2;
  const float *W0, *W1, *W2, *Wadd, *b0, *b1;
  ushort* outB;
  const float *projW, *projb;
  float* projOut;
  int M, nsrc, blkbase;
};

static __global__ __launch_bounds__(256) void gemm_all_k(GemmT g0, GemmT g1) {
  GemmT g = (g1.M > 0 && (int)blockIdx.x >= g1.blkbase) ? g1 : g0;
  __shared__ float At[64 * 132];  // At[k*132 + row]
  __shared__ float Wt[64 * 68];   // Wt[k*68 + j]
  const ushort* As[3] = {g.A0, g.A1, g.A2};
  const float* Ws[3] = {g.W0, g.W1, g.W2};
  const int t = threadIdx.x;
  const int m0 = ((int)blockIdx.x - g.blkbase) * 128;
  const int tc = t & 15;
  const int tr = t >> 4;
  float acc[8][4];
#pragma unroll
  for (int r = 0; r < 8; ++r)
#pragma unroll
    for (int c = 0; c < 4; ++c) acc[r][c] = 0.f;

  for (int s = 0; s < g.nsrc; ++s) {
    if (s) __syncthreads();
    const float* W = Ws[s];
    const float* Wa = (s == g.nsrc - 1) ? g.Wadd : nullptr;
    for (int i = 0; i < 4; ++i) {
      int f = i * 256 + t;
      int j = f & 63;
      int c4 = f >> 6;
      float4 v = *(const float4*)(W + j * 64 + c4 * 4);
      if (Wa) {
        float4 v2 = *(const float4*)(Wa + j * 64 + c4 * 4);
        v.x += v2.x; v.y += v2.y; v.z += v2.z; v.w += v2.w;
      }
      Wt[(c4 * 4 + 0) * 68 + j] = v.x;
      Wt[(c4 * 4 + 1) * 68 + j] = v.y;
      Wt[(c4 * 4 + 2) * 68 + j] = v.z;
      Wt[(c4 * 4 + 3) * 68 + j] = v.w;
    }
    const ushort* A = As[s];
    for (int i = 0; i < 4; ++i) {
      int f = i * 256 + t;   // 1024 chunks of 8 bf16
      int row = f & 127;
      int c8 = f >> 7;       // [0,8)
      int m = m0 + row;
      uint4 u = make_uint4(0, 0, 0, 0);
      if (m < g.M) u = *(const uint4*)(A + (size_t)m * 64 + c8 * 8);
      At[(c8 * 8 + 0) * 132 + row] = bflo(u.x);
      At[(c8 * 8 + 1) * 132 + row] = bfhi(u.x);
      At[(c8 * 8 + 2) * 132 + row] = bflo(u.y);
      At[(c8 * 8 + 3) * 132 + row] = bfhi(u.y);
      At[(c8 * 8 + 4) * 132 + row] = bflo(u.z);
      At[(c8 * 8 + 5) * 132 + row] = bfhi(u.z);
      At[(c8 * 8 + 6) * 132 + row] = bflo(u.w);
      At[(c8 * 8 + 7) * 132 + row] = bfhi(u.w);
    }
    __syncthreads();

#pragma unroll 8
    for (int k = 0; k < 64; ++k) {
      float4 w = *(const float4*)(&Wt[k * 68 + tc * 4]);
      float4 a0 = *(const float4*)(&At[k * 132 + tr * 8]);
      float4 a1 = *(const float4*)(&At[k * 132 + tr * 8 + 4]);
      float av[8] = {a0.x, a0.y, a0.z, a0.w, a1.x, a1.y, a1.z, a1.w};
      float wv[4] = {w.x, w.y, w.z, w.w};
#pragma unroll
      for (int r = 0; r < 8; ++r)
#pragma unroll
        for (int c = 0; c < 4; ++c) acc[r][c] = fmaf(av[r], wv[c], acc[r][c]);
    }
  }

  float4 bv = make_float4(0.f, 0.f, 0.f, 0.f);
  if (g.b0) {
    float4 b0 = *(const float4*)(g.b0 + tc * 4);
    bv.x += b0.x; bv.y += b0.y; bv.z += b0.z; bv.w += b0.w;
  }
  if (g.b1) {
    float4 b1 = *(const float4*)(g.b1 + tc * 4);
    bv.x += b1.x; bv.y += b1.y; bv.z += b1.z; bv.w += b1.w;
  }

  float4 pw = make_float4(0.f, 0.f, 0.f, 0.f);
  float pb = 0.f;
  if (g.projOut) {
    pw = *(const float4*)(g.projW + tc * 4);
    pb = g.projb[0];
  }

#pragma unroll
  for (int r = 0; r < 8; ++r) {
    int m = m0 + tr * 8 + r;
    if (m < g.M) {
      float4 o;
      o.x = fmaxf(acc[r][0] + bv.x, 0.f);
      o.y = fmaxf(acc[r][1] + bv.y, 0.f);
      o.z = fmaxf(acc[r][2] + bv.z, 0.f);
      o.w = fmaxf(acc[r][3] + bv.w, 0.f);
      if (g.projOut) {
        float p = o.x * pw.x + o.y * pw.y + o.z * pw.z + o.w * pw.w;
        p += __shfl_xor(p, 1, 64);
        p += __shfl_xor(p, 2, 64);
        p += __shfl_xor(p, 4, 64);
        p += __shfl_xor(p, 8, 64);
        if (tc == 0) g.projOut[m] = p + pb;
      } else {
        ushort4 ob;
        ob.x = f2bf(o.x); ob.y = f2bf(o.y); ob.z = f2bf(o.z); ob.w = f2bf(o.w);
        *(ushort4*)(g.outB + (size_t)m * 64 + tc * 4) = ob;
      }
    }
  }
}

// ---------------- launch ----------------

extern "C" void kernel_launch(void* const* d_in, const int* in_sizes, int n_in, void* d_out,
                              int out_size, void* d_ws, size_t ws_size, hipStream_t stream) {
  const float* x_person = (const float*)d_in[0];
  const float* x_movie = (const float*)d_in[1];
  const int* acted_src = (const int*)d_in[2];
  const int* acted_dst = (const int*)d_in[3];
  const int* directed_src = (const int*)d_in[4];
  const int* directed_dst = (const int*)d_in[5];
  const int* www_src = (const int*)d_in[6];
  const int* www_dst = (const int*)d_in[7];
  const float* Wl_acted = (const float*)d_in[8];
  const float* bl_acted = (const float*)d_in[9];
  const float* Wr_acted = (const float*)d_in[10];
  const float* Wl_directed = (const float*)d_in[11];
  const float* bl_directed = (const float*)d_in[12];
  const float* Wr_directed = (const float*)d_in[13];
  const float* Wl_www = (const float*)d_in[14];
  const float* bl_www = (const float*)d_in[15];
  const float* Wr_www = (const float*)d_in[16];
  const float* lin_W = (const float*)d_in[17];
  const float* lin_b = (const float*)d_in[18];
  float* out = (float*)d_out;
  (void)in_sizes; (void)n_in; (void)out_size; (void)ws_size;

  char* base = (char*)d_ws;
  size_t pos = 0;
  auto carve = [&](size_t b) -> void* {
    void* r = base + pos;
    pos += (b + 255) & ~(size_t)255;
    return r;
  };
  int* off_a = (int*)carve((N_MOVIE + 1) * sizeof(int));
  int* off_d = (int*)carve((N_MOVIE + 1) * sizeof(int));
  int* off_w = (int*)carve((N_PERSON + 1) * sizeof(int));
  int* parts = (int*)carve(1024 * sizeof(int));
  int* csr_all = (int*)carve((size_t)E_TOTAL * sizeof(int));
  int* pairs = (int*)carve((size_t)E_TOTAL * sizeof(int));
  ushort* xpbf = (ushort*)carve((size_t)N_PERSON * H * sizeof(ushort));
  ushort* xmbf = (ushort*)carve((size_t)N_MOVIE * H * sizeof(ushort));
  ushort* xp0bf = (ushort*)carve((size_t)N_PERSON * H * sizeof(ushort));
  ushort* xm0bf = (ushort*)carve((size_t)N_MOVIE * H * sizeof(ushort));
  ushort* meanAbf = (ushort*)carve((size_t)N_MOVIE * H * sizeof(ushort));
  ushort* meanDbf = (ushort*)carve((size_t)N_MOVIE * H * sizeof(ushort));
  ushort* meanWbf = (ushort*)carve((size_t)N_PERSON * H * sizeof(ushort));

  // relation descriptors (A=acted, D=directed, W=www), contiguous in counts/edges
  RelP rA, rD, rW;
  rA.src = acted_src;  rA.dst = acted_dst;  rA.off = off_a;
  rA.E = E_ACTED;      rA.N = N_MOVIE;
  rA.nblk = (E_ACTED + CH - 1) / CH;      rA.nbuk = (N_MOVIE + 255) >> SH;
  rD.src = directed_src; rD.dst = directed_dst; rD.off = off_d;
  rD.E = E_DIRECTED;     rD.N = N_MOVIE;
  rD.nblk = (E_DIRECTED + CH - 1) / CH;   rD.nbuk = (N_MOVIE + 255) >> SH;
  rW.src = www_src;    rW.dst = www_dst;  rW.off = off_w;
  rW.E = E_WWW;        rW.N = N_PERSON;
  rW.nblk = (E_WWW + CH - 1) / CH;        rW.nbuk = (N_PERSON + 255) >> SH;
  rA.blkbase = 0;                 rD.blkbase = rA.nblk;           rW.blkbase = rA.nblk + rD.nblk;
  rA.bukbase = 0;                 rD.bukbase = rA.nbuk;           rW.bukbase = rA.nbuk + rD.nbuk;
  rA.cbase = 0;                   rD.cbase = rA.nbuk * rA.nblk;
  rW.cbase = rD.cbase + rD.nbuk * rD.nblk;
  rA.ebase = 0;                   rD.ebase = E_ACTED;             rW.ebase = E_ACTED + E_DIRECTED;
  const int n_total = rW.cbase + rW.nbuk * rW.nblk;
  const int nblk_total = rW.blkbase + rW.nblk;
  const int nbuk_total = rW.bukbase + rW.nbuk;

  int* counts = (int*)carve((size_t)n_total * sizeof(int));
  int* off_bb = (int*)carve((size_t)(n_total + 1) * sizeof(int));

  // ---- CSR build (all relations in each launch) ----
  part_count_all_k<<<nblk_total, 256, 0, stream>>>(rA, rD, rW, counts);
  int nb = (n_total + 1023) / 1024;
  scan_block_k<<<nb, 1024, 0, stream>>>(counts, n_total, off_bb, parts);
  scan_block_k<<<1, 1024, 0, stream>>>(parts, nb, parts, nullptr);
  add_off_k<<<(n_total + 1 + 1023) / 1024, 1024, 0, stream>>>(off_bb, n_total, parts, E_TOTAL);
  part_scatter_all_k<<<nblk_total, 256, 0, stream>>>(rA, rD, rW, off_bb, pairs);
  fine_sort_all_k<<<nbuk_total, 256, 0, stream>>>(rA, rD, rW, off_bb, pairs, csr_all);

  // ---- bf16 casts ----
  cast_all_k<<<2048, 256, 0, stream>>>(x_person, xpbf, N_PERSON * H / 4, x_movie, xmbf,
                                       N_MOVIE * H / 4);

  const int nbA = (N_MOVIE + 3) / 4, nbD = (N_MOVIE + 3) / 4, nbW = (N_PERSON + 3) / 4;
  const int gmM = (N_MOVIE + 127) / 128, gmP = (N_PERSON + 127) / 128;

  // ---- layer 1 pulls: acted, directed, www from xpbf ----
  {
    PullT pA = {xpbf, off_a, meanAbf, N_MOVIE, 0};
    PullT pD = {xpbf, off_d, meanDbf, N_MOVIE, nbA};
    PullT pW = {xpbf, off_w, meanWbf, N_PERSON, nbA + nbD};
    pull_all_k<<<nbA + nbD + nbW, 256, 0, stream>>>(pA, pD, pW, csr_all);
  }
  // ---- layer 1 GEMMs: movie (3 srcs) + person (2 srcs), one launch ----
  {
    GemmT gM = {meanAbf, meanDbf, xmbf,
                Wl_acted, Wl_directed, Wr_acted, Wr_directed, bl_acted, bl_directed,
                xm0bf, nullptr, nullptr, nullptr, N_MOVIE, 3, 0};
    GemmT gP = {meanWbf, xpbf, nullptr,
                Wl_www, Wr_www, nullptr, nullptr, bl_www, nullptr,
                xp0bf, nullptr, nullptr, nullptr, N_PERSON, 2, gmM};
    gemm_all_k<<<gmM + gmP, 256, 0, stream>>>(gM, gP);
  }
  // ---- layer 2 pulls: acted, directed from xp0bf ----
  {
    PullT pA = {xp0bf, off_a, meanAbf, N_MOVIE, 0};
    PullT pD = {xp0bf, off_d, meanDbf, N_MOVIE, nbA};
    PullT pZ = {nullptr, nullptr, nullptr, 0, 0};
    pull_all_k<<<nbA + nbD, 256, 0, stream>>>(pA, pD, pZ, csr_all);
  }
  // ---- layer 2 movie GEMM with fused final projection ----
  {
    GemmT gM = {meanAbf, meanDbf, xm0bf,
                Wl_acted + 4096, Wl_directed + 4096, Wr_acted + 4096, Wr_directed + 4096,
                bl_acted + 64, bl_directed + 64,
                nullptr, lin_W, lin_b, out, N_MOVIE, 3, 0};
    GemmT gZ = {nullptr, nullptr, nullptr, nullptr, nullptr, nullptr, nullptr, nullptr, nullptr,
                nullptr, nullptr, nullptr, nullptr, 0, 0, 0};
    gemm_all_k<<<gmM, 256, 0, stream>>>(gM, gZ);
  }
}

// Round 6
// 467.618 us; speedup vs baseline: 3.0508x; 1.1147x over previous
//
#include <hip/hip_runtime.h>

#define H 64
#define N_PERSON 200000
#define N_MOVIE 100000
#define E_ACTED 1600000
#define E_DIRECTED 200000
#define E_WWW 3200000
#define E_TOTAL (E_ACTED + E_DIRECTED + E_WWW)

#define SH 8          // bucket = dst >> 8 (256 dsts per bucket)
#define CH 16384      // edges per partition block

static __device__ __forceinline__ ushort f2bf(float f) {
  uint u = __float_as_uint(f);
  uint r = (u + 0x7FFFu + ((u >> 16) & 1u)) >> 16;
  return (ushort)r;
}
static __device__ __forceinline__ float bflo(uint u) { return __uint_as_float(u << 16); }
static __device__ __forceinline__ float bfhi(uint u) { return __uint_as_float(u & 0xFFFF0000u); }
// high bf16 with low-mantissa garbage (free; rel err <= 2^-7, used in pull accumulation only)
static __device__ __forceinline__ float bfhiq(uint u) { return __uint_as_float(u); }
static __device__ __forceinline__ uint packbf(float lo, float hi) {
  return (uint)f2bf(lo) | ((uint)f2bf(hi) << 16);
}

// ---------------- relation descriptor ----------------

struct RelP {
  const int* src; const int* dst; int* off;
  int E, N, nblk, nbuk, blkbase, bukbase, cbase, ebase;
};

// ---------------- fp32 -> bf16 cast (two tensors, one launch) ----------------

static __global__ __launch_bounds__(256) void cast_all_k(const float* __restrict__ i0,
                                                         ushort* __restrict__ o0, int n0,
                                                         const float* __restrict__ i1,
                                                         ushort* __restrict__ o1, int n1) {
  int i = blockIdx.x * 256 + threadIdx.x;
  int stride = gridDim.x * 256;
  int nt = n0 + n1;
  for (; i < nt; i += stride) {
    const float4* in; ushort4* out; int idx;
    if (i < n0) { in = (const float4*)i0; out = (ushort4*)o0; idx = i; }
    else { in = (const float4*)i1; out = (ushort4*)o1; idx = i - n0; }
    float4 v = in[idx];
    ushort4 o;
    o.x = f2bf(v.x); o.y = f2bf(v.y); o.z = f2bf(v.z); o.w = f2bf(v.w);
    out[idx] = o;
  }
}

// ---------------- scan helpers ----------------

static __global__ __launch_bounds__(1024) void scan_block_k(const int* __restrict__ in, int n,
                                                            int* __restrict__ out,
                                                            int* __restrict__ partials) {
  __shared__ int sm[1024];
  int tid = threadIdx.x;
  int gid = blockIdx.x * 1024 + tid;
  int v = (gid < n) ? in[gid] : 0;
  sm[tid] = v;
  __syncthreads();
  for (int d = 1; d < 1024; d <<= 1) {
    int t = (tid >= d) ? sm[tid - d] : 0;
    __syncthreads();
    if (tid >= d) sm[tid] += t;
    __syncthreads();
  }
  if (gid < n) out[gid] = sm[tid] - v;  // exclusive
  if (tid == 1023 && partials) partials[blockIdx.x] = sm[1023];
}

static __global__ __launch_bounds__(1024) void add_off_k(int* __restrict__ off, int n,
                                                         const int* __restrict__ parts, int total) {
  int gid = blockIdx.x * 1024 + threadIdx.x;
  if (gid < n) off[gid] += parts[gid >> 10];
  else if (gid == n) off[gid] = total;
}

// ---------------- two-level counting sort, all relations fused ----------------

static __global__ __launch_bounds__(256) void part_count_all_k(RelP a, RelP b, RelP c,
                                                               int* __restrict__ counts) {
  __shared__ int hist[800];
  int blk = blockIdx.x, t = threadIdx.x;
  RelP r = (blk >= c.blkbase) ? c : (blk >= b.blkbase) ? b : a;
  int lb = blk - r.blkbase;
  for (int i = t; i < r.nbuk; i += 256) hist[i] = 0;
  __syncthreads();
  int e0 = lb * CH, e1 = min(e0 + CH, r.E);
  for (int e = e0 + t; e < e1; e += 256) atomicAdd(&hist[r.dst[e] >> SH], 1);
  __syncthreads();
  for (int i = t; i < r.nbuk; i += 256) counts[r.cbase + i * r.nblk + lb] = hist[i];
}

static __global__ __launch_bounds__(256) void part_scatter_all_k(RelP a, RelP b, RelP c,
                                                                 const int* __restrict__ off_bb,
                                                                 int* __restrict__ pairs) {
  __shared__ int cur[800];
  int blk = blockIdx.x, t = threadIdx.x;
  RelP r = (blk >= c.blkbase) ? c : (blk >= b.blkbase) ? b : a;
  int lb = blk - r.blkbase;
  for (int i = t; i < r.nbuk; i += 256) cur[i] = off_bb[r.cbase + i * r.nblk + lb];
  __syncthreads();
  int e0 = lb * CH, e1 = min(e0 + CH, r.E);
  for (int e = e0 + t; e < e1; e += 256) {
    int d = r.dst[e];
    int pos = atomicAdd(&cur[d >> SH], 1);
    pairs[pos] = ((d & 255) << 24) | r.src[e];  // src < 2^18
  }
}

static __global__ __launch_bounds__(256) void fine_sort_all_k(RelP a, RelP b, RelP c,
                                                              const int* __restrict__ off_bb,
                                                              const int* __restrict__ pairs,
                                                              int* __restrict__ csr) {
  __shared__ int hist[256];
  __shared__ int sc[256];
  int bb = blockIdx.x, t = threadIdx.x;
  RelP r = (bb >= c.bukbase) ? c : (bb >= b.bukbase) ? b : a;
  int bkt = bb - r.bukbase;
  int bstart = off_bb[r.cbase + bkt * r.nblk];
  int bend = (bkt + 1 < r.nbuk) ? off_bb[r.cbase + (bkt + 1) * r.nblk] : (r.ebase + r.E);
  int base = bkt << SH;
  hist[t] = 0;
  __syncthreads();
  for (int e = bstart + t; e < bend; e += 256) atomicAdd(&hist[((uint)pairs[e]) >> 24], 1);
  __syncthreads();
  sc[t] = hist[t];
  __syncthreads();
  for (int d = 1; d < 256; d <<= 1) {
    int u = (t >= d) ? sc[t - d] : 0;
    __syncthreads();
    sc[t] += u;
    __syncthreads();
  }
  int excl = sc[t] - hist[t];
  if (base + t < r.N) r.off[base + t] = bstart + excl;  // global edge index
  if (bkt == r.nbuk - 1 && t == 0) r.off[r.N] = r.ebase + r.E;
  hist[t] = excl;  // reuse as cursor
  __syncthreads();
  for (int e = bstart + t; e < bend; e += 256) {
    int p = pairs[e];
    int pos = bstart + atomicAdd(&hist[((uint)p) >> 24], 1);
    csr[pos] = p & 0x00FFFFFF;
  }
}

// ---------------- multi-task pull mean (bf16 in, bf16 out) ----------------
// 8 dsts per wave: lane = (g = lane>>3 dst slot, fo = lane&7 feature octet).
// Each 8-lane group iterates its dst's edges serially (2 gathers in flight),
// accumulators lane-private -> no cross-lane reduce; all 64 lanes write (1KB/wave).

struct PullT { const ushort* xsrc; const int* off; ushort* mean; int n; int blkbase; };

static __global__ __launch_bounds__(256) void pull_all_k(PullT t0, PullT t1, PullT t2,
                                                         const int* __restrict__ csr) {
  int blk = blockIdx.x;
  PullT tk;
  if (t2.n > 0 && blk >= t2.blkbase) tk = t2;
  else if (blk >= t1.blkbase) tk = t1;
  else tk = t0;
  int lane = threadIdx.x & 63;
  int g = lane >> 3;   // dst slot within wave
  int fo = lane & 7;   // feature octet
  int d = ((blk - tk.blkbase) * 4 + (threadIdx.x >> 6)) * 8 + g;
  bool dok = d < tk.n;
  int dd = dok ? d : (tk.n - 1);
  int e0 = tk.off[dd];
  int e1 = tk.off[dd + 1];
  int cnt = dok ? (e1 - e0) : 0;
  // wave-wide max degree (groups differ in lane bits 3..5)
  int mx = cnt;
  mx = max(mx, __shfl_xor(mx, 8, 64));
  mx = max(mx, __shfl_xor(mx, 16, 64));
  mx = max(mx, __shfl_xor(mx, 32, 64));

  const ushort* __restrict__ xrow = tk.xsrc + fo * 8;
  float a0 = 0.f, a1 = 0.f, a2 = 0.f, a3 = 0.f, a4 = 0.f, a5 = 0.f, a6 = 0.f, a7 = 0.f;

  int i = 0;
  for (; i + 2 <= mx; i += 2) {
    if (i + 1 < cnt) {  // both edges valid: 2 gathers in flight
      int s0 = csr[e0 + i];
      int s1 = csr[e0 + i + 1];
      uint4 u0 = *(const uint4*)(xrow + (size_t)s0 * 64);
      uint4 u1 = *(const uint4*)(xrow + (size_t)s1 * 64);
      a0 += bflo(u0.x); a1 += bfhiq(u0.x);
      a2 += bflo(u0.y); a3 += bfhiq(u0.y);
      a4 += bflo(u0.z); a5 += bfhiq(u0.z);
      a6 += bflo(u0.w); a7 += bfhiq(u0.w);
      a0 += bflo(u1.x); a1 += bfhiq(u1.x);
      a2 += bflo(u1.y); a3 += bfhiq(u1.y);
      a4 += bflo(u1.z); a5 += bfhiq(u1.z);
      a6 += bflo(u1.w); a7 += bfhiq(u1.w);
    } else if (i < cnt) {  // last odd edge of this group
      int s0 = csr[e0 + i];
      uint4 u0 = *(const uint4*)(xrow + (size_t)s0 * 64);
      a0 += bflo(u0.x); a1 += bfhiq(u0.x);
      a2 += bflo(u0.y); a3 += bfhiq(u0.y);
      a4 += bflo(u0.z); a5 += bfhiq(u0.z);
      a6 += bflo(u0.w); a7 += bfhiq(u0.w);
    }
  }
  if (i < mx && i < cnt) {
    int s0 = csr[e0 + i];
    uint4 u0 = *(const uint4*)(xrow + (size_t)s0 * 64);
    a0 += bflo(u0.x); a1 += bfhiq(u0.x);
    a2 += bflo(u0.y); a3 += bfhiq(u0.y);
    a4 += bflo(u0.z); a5 += bfhiq(u0.z);
    a6 += bflo(u0.w); a7 += bfhiq(u0.w);
  }

  if (dok) {
    float inv = 1.0f / fmaxf((float)cnt, 1.0f);
    uint4 o;
    o.x = packbf(a0 * inv, a1 * inv);
    o.y = packbf(a2 * inv, a3 * inv);
    o.z = packbf(a4 * inv, a5 * inv);
    o.w = packbf(a6 * inv, a7 * inv);
    *(uint4*)(tk.mean + (size_t)d * 64 + fo * 8) = o;
  }
}

// ---- fused GEMM (bf16 A, fp32 W/acc): C = sum_s A_s @ (W_s [+Wadd])^T + b0 + b1, relu;
//      output bf16, or fused 64->1 projection. Two tasks per launch. ----

struct GemmT {
  const ushort *A0, *A1, *A2;
  const float *W0, *W1, *W2, *Wadd, *b0, *b1;
  ushort* outB;
  const float *projW, *projb;
  float* projOut;
  int M, nsrc, blkbase;
};

static __global__ __launch_bounds__(256) void gemm_all_k(GemmT g0, GemmT g1) {
  GemmT g = (g1.M > 0 && (int)blockIdx.x >= g1.blkbase) ? g1 : g0;
  __shared__ float At[64 * 132];  // At[k*132 + row]
  __shared__ float Wt[64 * 68];   // Wt[k*68 + j]
  const ushort* As[3] = {g.A0, g.A1, g.A2};
  const float* Ws[3] = {g.W0, g.W1, g.W2};
  const int t = threadIdx.x;
  const int m0 = ((int)blockIdx.x - g.blkbase) * 128;
  const int tc = t & 15;
  const int tr = t >> 4;
  float acc[8][4];
#pragma unroll
  for (int r = 0; r < 8; ++r)
#pragma unroll
    for (int c = 0; c < 4; ++c) acc[r][c] = 0.f;

  for (int s = 0; s < g.nsrc; ++s) {
    if (s) __syncthreads();
    const float* W = Ws[s];
    const float* Wa = (s == g.nsrc - 1) ? g.Wadd : nullptr;
    for (int i = 0; i < 4; ++i) {
      int f = i * 256 + t;
      int j = f & 63;
      int c4 = f >> 6;
      float4 v = *(const float4*)(W + j * 64 + c4 * 4);
      if (Wa) {
        float4 v2 = *(const float4*)(Wa + j * 64 + c4 * 4);
        v.x += v2.x; v.y += v2.y; v.z += v2.z; v.w += v2.w;
      }
      Wt[(c4 * 4 + 0) * 68 + j] = v.x;
      Wt[(c4 * 4 + 1) * 68 + j] = v.y;
      Wt[(c4 * 4 + 2) * 68 + j] = v.z;
      Wt[(c4 * 4 + 3) * 68 + j] = v.w;
    }
    const ushort* A = As[s];
    for (int i = 0; i < 4; ++i) {
      int f = i * 256 + t;   // 1024 chunks of 8 bf16
      int row = f & 127;
      int c8 = f >> 7;       // [0,8)
      int m = m0 + row;
      uint4 u = make_uint4(0, 0, 0, 0);
      if (m < g.M) u = *(const uint4*)(A + (size_t)m * 64 + c8 * 8);
      At[(c8 * 8 + 0) * 132 + row] = bflo(u.x);
      At[(c8 * 8 + 1) * 132 + row] = bfhi(u.x);
      At[(c8 * 8 + 2) * 132 + row] = bflo(u.y);
      At[(c8 * 8 + 3) * 132 + row] = bfhi(u.y);
      At[(c8 * 8 + 4) * 132 + row] = bflo(u.z);
      At[(c8 * 8 + 5) * 132 + row] = bfhi(u.z);
      At[(c8 * 8 + 6) * 132 + row] = bflo(u.w);
      At[(c8 * 8 + 7) * 132 + row] = bfhi(u.w);
    }
    __syncthreads();

#pragma unroll 8
    for (int k = 0; k < 64; ++k) {
      float4 w = *(const float4*)(&Wt[k * 68 + tc * 4]);
      float4 a0 = *(const float4*)(&At[k * 132 + tr * 8]);
      float4 a1 = *(const float4*)(&At[k * 132 + tr * 8 + 4]);
      float av[8] = {a0.x, a0.y, a0.z, a0.w, a1.x, a1.y, a1.z, a1.w};
      float wv[4] = {w.x, w.y, w.z, w.w};
#pragma unroll
      for (int r = 0; r < 8; ++r)
#pragma unroll
        for (int c = 0; c < 4; ++c) acc[r][c] = fmaf(av[r], wv[c], acc[r][c]);
    }
  }

  float4 bv = make_float4(0.f, 0.f, 0.f, 0.f);
  if (g.b0) {
    float4 b0 = *(const float4*)(g.b0 + tc * 4);
    bv.x += b0.x; bv.y += b0.y; bv.z += b0.z; bv.w += b0.w;
  }
  if (g.b1) {
    float4 b1 = *(const float4*)(g.b1 + tc * 4);
    bv.x += b1.x; bv.y += b1.y; bv.z += b1.z; bv.w += b1.w;
  }

  float4 pw = make_float4(0.f, 0.f, 0.f, 0.f);
  float pb = 0.f;
  if (g.projOut) {
    pw = *(const float4*)(g.projW + tc * 4);
    pb = g.projb[0];
  }

#pragma unroll
  for (int r = 0; r < 8; ++r) {
    int m = m0 + tr * 8 + r;
    if (m < g.M) {
      float4 o;
      o.x = fmaxf(acc[r][0] + bv.x, 0.f);
      o.y = fmaxf(acc[r][1] + bv.y, 0.f);
      o.z = fmaxf(acc[r][2] + bv.z, 0.f);
      o.w = fmaxf(acc[r][3] + bv.w, 0.f);
      if (g.projOut) {
        float p = o.x * pw.x + o.y * pw.y + o.z * pw.z + o.w * pw.w;
        p += __shfl_xor(p, 1, 64);
        p += __shfl_xor(p, 2, 64);
        p += __shfl_xor(p, 4, 64);
        p += __shfl_xor(p, 8, 64);
        if (tc == 0) g.projOut[m] = p + pb;
      } else {
        ushort4 ob;
        ob.x = f2bf(o.x); ob.y = f2bf(o.y); ob.z = f2bf(o.z); ob.w = f2bf(o.w);
        *(ushort4*)(g.outB + (size_t)m * 64 + tc * 4) = ob;
      }
    }
  }
}

// ---------------- launch ----------------

extern "C" void kernel_launch(void* const* d_in, const int* in_sizes, int n_in, void* d_out,
                              int out_size, void* d_ws, size_t ws_size, hipStream_t stream) {
  const float* x_person = (const float*)d_in[0];
  const float* x_movie = (const float*)d_in[1];
  const int* acted_src = (const int*)d_in[2];
  const int* acted_dst = (const int*)d_in[3];
  const int* directed_src = (const int*)d_in[4];
  const int* directed_dst = (const int*)d_in[5];
  const int* www_src = (const int*)d_in[6];
  const int* www_dst = (const int*)d_in[7];
  const float* Wl_acted = (const float*)d_in[8];
  const float* bl_acted = (const float*)d_in[9];
  const float* Wr_acted = (const float*)d_in[10];
  const float* Wl_directed = (const float*)d_in[11];
  const float* bl_directed = (const float*)d_in[12];
  const float* Wr_directed = (const float*)d_in[13];
  const float* Wl_www = (const float*)d_in[14];
  const float* bl_www = (const float*)d_in[15];
  const float* Wr_www = (const float*)d_in[16];
  const float* lin_W = (const float*)d_in[17];
  const float* lin_b = (const float*)d_in[18];
  float* out = (float*)d_out;
  (void)in_sizes; (void)n_in; (void)out_size; (void)ws_size;

  char* base = (char*)d_ws;
  size_t pos = 0;
  auto carve = [&](size_t b) -> void* {
    void* r = base + pos;
    pos += (b + 255) & ~(size_t)255;
    return r;
  };
  int* off_a = (int*)carve((N_MOVIE + 1) * sizeof(int));
  int* off_d = (int*)carve((N_MOVIE + 1) * sizeof(int));
  int* off_w = (int*)carve((N_PERSON + 1) * sizeof(int));
  int* parts = (int*)carve(1024 * sizeof(int));
  int* csr_all = (int*)carve((size_t)E_TOTAL * sizeof(int));
  int* pairs = (int*)carve((size_t)E_TOTAL * sizeof(int));
  ushort* xpbf = (ushort*)carve((size_t)N_PERSON * H * sizeof(ushort));
  ushort* xmbf = (ushort*)carve((size_t)N_MOVIE * H * sizeof(ushort));
  ushort* xp0bf = (ushort*)carve((size_t)N_PERSON * H * sizeof(ushort));
  ushort* xm0bf = (ushort*)carve((size_t)N_MOVIE * H * sizeof(ushort));
  ushort* meanAbf = (ushort*)carve((size_t)N_MOVIE * H * sizeof(ushort));
  ushort* meanDbf = (ushort*)carve((size_t)N_MOVIE * H * sizeof(ushort));
  ushort* meanWbf = (ushort*)carve((size_t)N_PERSON * H * sizeof(ushort));

  // relation descriptors (A=acted, D=directed, W=www), contiguous in counts/edges
  RelP rA, rD, rW;
  rA.src = acted_src;  rA.dst = acted_dst;  rA.off = off_a;
  rA.E = E_ACTED;      rA.N = N_MOVIE;
  rA.nblk = (E_ACTED + CH - 1) / CH;      rA.nbuk = (N_MOVIE + 255) >> SH;
  rD.src = directed_src; rD.dst = directed_dst; rD.off = off_d;
  rD.E = E_DIRECTED;     rD.N = N_MOVIE;
  rD.nblk = (E_DIRECTED + CH - 1) / CH;   rD.nbuk = (N_MOVIE + 255) >> SH;
  rW.src = www_src;    rW.dst = www_dst;  rW.off = off_w;
  rW.E = E_WWW;        rW.N = N_PERSON;
  rW.nblk = (E_WWW + CH - 1) / CH;        rW.nbuk = (N_PERSON + 255) >> SH;
  rA.blkbase = 0;                 rD.blkbase = rA.nblk;           rW.blkbase = rA.nblk + rD.nblk;
  rA.bukbase = 0;                 rD.bukbase = rA.nbuk;           rW.bukbase = rA.nbuk + rD.nbuk;
  rA.cbase = 0;                   rD.cbase = rA.nbuk * rA.nblk;
  rW.cbase = rD.cbase + rD.nbuk * rD.nblk;
  rA.ebase = 0;                   rD.ebase = E_ACTED;             rW.ebase = E_ACTED + E_DIRECTED;
  const int n_total = rW.cbase + rW.nbuk * rW.nblk;
  const int nblk_total = rW.blkbase + rW.nblk;
  const int nbuk_total = rW.bukbase + rW.nbuk;

  int* counts = (int*)carve((size_t)n_total * sizeof(int));
  int* off_bb = (int*)carve((size_t)(n_total + 1) * sizeof(int));

  // ---- CSR build (all relations in each launch) ----
  part_count_all_k<<<nblk_total, 256, 0, stream>>>(rA, rD, rW, counts);
  int nb = (n_total + 1023) / 1024;
  scan_block_k<<<nb, 1024, 0, stream>>>(counts, n_total, off_bb, parts);
  scan_block_k<<<1, 1024, 0, stream>>>(parts, nb, parts, nullptr);
  add_off_k<<<(n_total + 1 + 1023) / 1024, 1024, 0, stream>>>(off_bb, n_total, parts, E_TOTAL);
  part_scatter_all_k<<<nblk_total, 256, 0, stream>>>(rA, rD, rW, off_bb, pairs);
  fine_sort_all_k<<<nbuk_total, 256, 0, stream>>>(rA, rD, rW, off_bb, pairs, csr_all);

  // ---- bf16 casts ----
  cast_all_k<<<2048, 256, 0, stream>>>(x_person, xpbf, N_PERSON * H / 4, x_movie, xmbf,
                                       N_MOVIE * H / 4);

  // 32 dsts per block (4 waves x 8 dsts)
  const int nbA = (N_MOVIE + 31) / 32, nbD = (N_MOVIE + 31) / 32, nbW = (N_PERSON + 31) / 32;
  const int gmM = (N_MOVIE + 127) / 128, gmP = (N_PERSON + 127) / 128;

  // ---- layer 1 pulls: acted, directed, www from xpbf ----
  {
    PullT pA = {xpbf, off_a, meanAbf, N_MOVIE, 0};
    PullT pD = {xpbf, off_d, meanDbf, N_MOVIE, nbA};
    PullT pW = {xpbf, off_w, meanWbf, N_PERSON, nbA + nbD};
    pull_all_k<<<nbA + nbD + nbW, 256, 0, stream>>>(pA, pD, pW, csr_all);
  }
  // ---- layer 1 GEMMs: movie (3 srcs) + person (2 srcs), one launch ----
  {
    GemmT gM = {meanAbf, meanDbf, xmbf,
                Wl_acted, Wl_directed, Wr_acted, Wr_directed, bl_acted, bl_directed,
                xm0bf, nullptr, nullptr, nullptr, N_MOVIE, 3, 0};
    GemmT gP = {meanWbf, xpbf, nullptr,
                Wl_www, Wr_www, nullptr, nullptr, bl_www, nullptr,
                xp0bf, nullptr, nullptr, nullptr, N_PERSON, 2, gmM};
    gemm_all_k<<<gmM + gmP, 256, 0, stream>>>(gM, gP);
  }
  // ---- layer 2 pulls: acted, directed from xp0bf ----
  {
    PullT pA = {xp0bf, off_a, meanAbf, N_MOVIE, 0};
    PullT pD = {xp0bf, off_d, meanDbf, N_MOVIE, nbA};
    PullT pZ = {nullptr, nullptr, nullptr, 0, 0};
    pull_all_k<<<nbA + nbD, 256, 0, stream>>>(pA, pD, pZ, csr_all);
  }
  // ---- layer 2 movie GEMM with fused final projection ----
  {
    GemmT gM = {meanAbf, meanDbf, xm0bf,
                Wl_acted + 4096, Wl_directed + 4096, Wr_acted + 4096, Wr_directed + 4096,
                bl_acted + 64, bl_directed + 64,
                nullptr, lin_W, lin_b, out, N_MOVIE, 3, 0};
    GemmT gZ = {nullptr, nullptr, nullptr, nullptr, nullptr, nullptr, nullptr, nullptr, nullptr,
                nullptr, nullptr, nullptr, nullptr, 0, 0, 0};
    gemm_all_k<<<gmM, 256, 0, stream>>>(gM, gZ);
  }
}

// Round 7
// 421.084 us; speedup vs baseline: 3.3880x; 1.1105x over previous
//
#include <hip/hip_runtime.h>

#define H 64
#define N_PERSON 200000
#define N_MOVIE 100000
#define E_ACTED 1600000
#define E_DIRECTED 200000
#define E_WWW 3200000
#define E_TOTAL (E_ACTED + E_DIRECTED + E_WWW)

#define SH 11         // bucket = dst >> 11 (2048 dsts per bucket)
#define NBIN 2048
#define CH 16384      // edges per partition block

static __device__ __forceinline__ ushort f2bf(float f) {
  uint u = __float_as_uint(f);
  uint r = (u + 0x7FFFu + ((u >> 16) & 1u)) >> 16;
  return (ushort)r;
}
static __device__ __forceinline__ float bflo(uint u) { return __uint_as_float(u << 16); }
static __device__ __forceinline__ float bfhi(uint u) { return __uint_as_float(u & 0xFFFF0000u); }
// high bf16 with low-mantissa garbage (free; rel err <= 2^-7, used in pull accumulation only)
static __device__ __forceinline__ float bfhiq(uint u) { return __uint_as_float(u); }
static __device__ __forceinline__ uint packbf(float lo, float hi) {
  return (uint)f2bf(lo) | ((uint)f2bf(hi) << 16);
}

// ---------------- relation descriptor ----------------

struct RelP {
  const int* src; const int* dst; int* off;
  int E, N, nblk, nbuk, blkbase, bukbase, cbase, ebase;
};

// ---------------- fp32 -> bf16 cast (two tensors, one launch) ----------------

static __global__ __launch_bounds__(256) void cast_all_k(const float* __restrict__ i0,
                                                         ushort* __restrict__ o0, int n0,
                                                         const float* __restrict__ i1,
                                                         ushort* __restrict__ o1, int n1) {
  int i = blockIdx.x * 256 + threadIdx.x;
  int stride = gridDim.x * 256;
  int nt = n0 + n1;
  for (; i < nt; i += stride) {
    const float4* in; ushort4* out; int idx;
    if (i < n0) { in = (const float4*)i0; out = (ushort4*)o0; idx = i; }
    else { in = (const float4*)i1; out = (ushort4*)o1; idx = i - n0; }
    float4 v = in[idx];
    ushort4 o;
    o.x = f2bf(v.x); o.y = f2bf(v.y); o.z = f2bf(v.z); o.w = f2bf(v.w);
    out[idx] = o;
  }
}

// ---------------- scan helpers ----------------

static __global__ __launch_bounds__(1024) void scan_block_k(const int* __restrict__ in, int n,
                                                            int* __restrict__ out,
                                                            int* __restrict__ partials) {
  __shared__ int sm[1024];
  int tid = threadIdx.x;
  int gid = blockIdx.x * 1024 + tid;
  int v = (gid < n) ? in[gid] : 0;
  sm[tid] = v;
  __syncthreads();
  for (int d = 1; d < 1024; d <<= 1) {
    int t = (tid >= d) ? sm[tid - d] : 0;
    __syncthreads();
    if (tid >= d) sm[tid] += t;
    __syncthreads();
  }
  if (gid < n) out[gid] = sm[tid] - v;  // exclusive
  if (tid == 1023 && partials) partials[blockIdx.x] = sm[1023];
}

static __global__ __launch_bounds__(1024) void add_off_k(int* __restrict__ off, int n,
                                                         const int* __restrict__ parts, int total) {
  int gid = blockIdx.x * 1024 + threadIdx.x;
  if (gid < n) off[gid] += parts[gid >> 10];
  else if (gid == n) off[gid] = total;
}

// ---------------- two-level counting sort, all relations fused ----------------

static __global__ __launch_bounds__(256) void part_count_all_k(RelP a, RelP b, RelP c,
                                                               int* __restrict__ counts) {
  __shared__ int hist[128];
  int blk = blockIdx.x, t = threadIdx.x;
  RelP r = (blk >= c.blkbase) ? c : (blk >= b.blkbase) ? b : a;
  int lb = blk - r.blkbase;
  for (int i = t; i < r.nbuk; i += 256) hist[i] = 0;
  __syncthreads();
  int e0 = lb * CH, e1 = min(e0 + CH, r.E);
  for (int e = e0 + t; e < e1; e += 256) atomicAdd(&hist[r.dst[e] >> SH], 1);
  __syncthreads();
  for (int i = t; i < r.nbuk; i += 256) counts[r.cbase + i * r.nblk + lb] = hist[i];
}

static __global__ __launch_bounds__(256) void part_scatter_all_k(RelP a, RelP b, RelP c,
                                                                 const int* __restrict__ off_bb,
                                                                 int* __restrict__ pairs) {
  __shared__ int cur[128];
  int blk = blockIdx.x, t = threadIdx.x;
  RelP r = (blk >= c.blkbase) ? c : (blk >= b.blkbase) ? b : a;
  int lb = blk - r.blkbase;
  for (int i = t; i < r.nbuk; i += 256) cur[i] = off_bb[r.cbase + i * r.nblk + lb];
  __syncthreads();
  int e0 = lb * CH, e1 = min(e0 + CH, r.E);
  int e = e0 + t;
  for (; e + 256 < e1; e += 512) {
    int d0 = r.dst[e], s0 = r.src[e];
    int d1 = r.dst[e + 256], s1 = r.src[e + 256];
    int p0 = atomicAdd(&cur[d0 >> SH], 1);
    int p1 = atomicAdd(&cur[d1 >> SH], 1);
    pairs[p0] = ((d0 & (NBIN - 1)) << 18) | s0;  // src < 2^18
    pairs[p1] = ((d1 & (NBIN - 1)) << 18) | s1;
  }
  if (e < e1) {
    int d0 = r.dst[e], s0 = r.src[e];
    int p0 = atomicAdd(&cur[d0 >> SH], 1);
    pairs[p0] = ((d0 & (NBIN - 1)) << 18) | s0;
  }
}

// one block (1024 thr) per coarse bucket: 2048-bin LDS counting sort
static __global__ __launch_bounds__(1024) void fine_sort_all_k(RelP a, RelP b, RelP c,
                                                               const int* __restrict__ off_bb,
                                                               const int* __restrict__ pairs,
                                                               int* __restrict__ csr) {
  __shared__ int hist[NBIN];
  __shared__ int sc[NBIN];
  int bb = blockIdx.x, t = threadIdx.x;
  RelP r = (bb >= c.bukbase) ? c : (bb >= b.bukbase) ? b : a;
  int bkt = bb - r.bukbase;
  int bstart = off_bb[r.cbase + bkt * r.nblk];
  int bend = (bkt + 1 < r.nbuk) ? off_bb[r.cbase + (bkt + 1) * r.nblk] : (r.ebase + r.E);
  int base = bkt << SH;
  hist[t] = 0; hist[t + 1024] = 0;
  __syncthreads();
  for (int e = bstart + t; e < bend; e += 1024) atomicAdd(&hist[((uint)pairs[e]) >> 18], 1);
  __syncthreads();
  sc[t] = hist[t]; sc[t + 1024] = hist[t + 1024];
  __syncthreads();
  for (int d = 1; d < NBIN; d <<= 1) {
    int v0 = (t >= d) ? sc[t - d] : 0;
    int v1 = (t + 1024 >= d) ? sc[t + 1024 - d] : 0;
    __syncthreads();
    sc[t] += v0; sc[t + 1024] += v1;
    __syncthreads();
  }
  // exclusive offsets + off[] writes (2 bins per thread)
  int ex0 = sc[t] - hist[t];
  int ex1 = sc[t + 1024] - hist[t + 1024];
  if (base + t < r.N) r.off[base + t] = bstart + ex0;
  if (base + t + 1024 < r.N) r.off[base + t + 1024] = bstart + ex1;
  if (bkt == r.nbuk - 1 && t == 0) r.off[r.N] = r.ebase + r.E;
  hist[t] = ex0; hist[t + 1024] = ex1;  // reuse as cursors
  __syncthreads();
  for (int e = bstart + t; e < bend; e += 1024) {
    int p = pairs[e];
    int pos = bstart + atomicAdd(&hist[((uint)p) >> 18], 1);
    csr[pos] = p & 0x3FFFF;
  }
}

// ---------------- multi-task pull mean (bf16 in, bf16 out) ----------------
// 8 dsts per wave: lane = (g = lane>>3 dst slot, fo = lane&7 feature octet).

struct PullT { const ushort* xsrc; const int* off; ushort* mean; int n; int blkbase; };

static __global__ __launch_bounds__(256) void pull_all_k(PullT t0, PullT t1, PullT t2,
                                                         const int* __restrict__ csr) {
  int blk = blockIdx.x;
  PullT tk;
  if (t2.n > 0 && blk >= t2.blkbase) tk = t2;
  else if (blk >= t1.blkbase) tk = t1;
  else tk = t0;
  int lane = threadIdx.x & 63;
  int g = lane >> 3;   // dst slot within wave
  int fo = lane & 7;   // feature octet
  int d = ((blk - tk.blkbase) * 4 + (threadIdx.x >> 6)) * 8 + g;
  bool dok = d < tk.n;
  int dd = dok ? d : (tk.n - 1);
  int e0 = tk.off[dd];
  int e1 = tk.off[dd + 1];
  int cnt = dok ? (e1 - e0) : 0;
  int mx = cnt;
  mx = max(mx, __shfl_xor(mx, 8, 64));
  mx = max(mx, __shfl_xor(mx, 16, 64));
  mx = max(mx, __shfl_xor(mx, 32, 64));

  const ushort* __restrict__ xrow = tk.xsrc + fo * 8;
  float a0 = 0.f, a1 = 0.f, a2 = 0.f, a3 = 0.f, a4 = 0.f, a5 = 0.f, a6 = 0.f, a7 = 0.f;

  int i = 0;
  for (; i + 2 <= mx; i += 2) {
    if (i + 1 < cnt) {
      int s0 = csr[e0 + i];
      int s1 = csr[e0 + i + 1];
      uint4 u0 = *(const uint4*)(xrow + (size_t)s0 * 64);
      uint4 u1 = *(const uint4*)(xrow + (size_t)s1 * 64);
      a0 += bflo(u0.x); a1 += bfhiq(u0.x);
      a2 += bflo(u0.y); a3 += bfhiq(u0.y);
      a4 += bflo(u0.z); a5 += bfhiq(u0.z);
      a6 += bflo(u0.w); a7 += bfhiq(u0.w);
      a0 += bflo(u1.x); a1 += bfhiq(u1.x);
      a2 += bflo(u1.y); a3 += bfhiq(u1.y);
      a4 += bflo(u1.z); a5 += bfhiq(u1.z);
      a6 += bflo(u1.w); a7 += bfhiq(u1.w);
    } else if (i < cnt) {
      int s0 = csr[e0 + i];
      uint4 u0 = *(const uint4*)(xrow + (size_t)s0 * 64);
      a0 += bflo(u0.x); a1 += bfhiq(u0.x);
      a2 += bflo(u0.y); a3 += bfhiq(u0.y);
      a4 += bflo(u0.z); a5 += bfhiq(u0.z);
      a6 += bflo(u0.w); a7 += bfhiq(u0.w);
    }
  }
  if (i < mx && i < cnt) {
    int s0 = csr[e0 + i];
    uint4 u0 = *(const uint4*)(xrow + (size_t)s0 * 64);
    a0 += bflo(u0.x); a1 += bfhiq(u0.x);
    a2 += bflo(u0.y); a3 += bfhiq(u0.y);
    a4 += bflo(u0.z); a5 += bfhiq(u0.z);
    a6 += bflo(u0.w); a7 += bfhiq(u0.w);
  }

  if (dok) {
    float inv = 1.0f / fmaxf((float)cnt, 1.0f);
    uint4 o;
    o.x = packbf(a0 * inv, a1 * inv);
    o.y = packbf(a2 * inv, a3 * inv);
    o.z = packbf(a4 * inv, a5 * inv);
    o.w = packbf(a6 * inv, a7 * inv);
    *(uint4*)(tk.mean + (size_t)d * 64 + fo * 8) = o;
  }
}

// ---- fused GEMM (bf16 A, fp32 W/acc): C = sum_s A_s @ (W_s [+Wadd])^T + b0 + b1, relu;
//      output bf16, or fused 64->1 projection. Two tasks per launch. ----

struct GemmT {
  const ushort *A0, *A1, *A2;
  const float *W0, *W1, *W2, *Wadd, *b0, *b1;
  ushort* outB;
  const float *projW, *projb;
  float* projOut;
  int M, nsrc, blkbase;
};

static __global__ __launch_bounds__(256) void gemm_all_k(GemmT g0, GemmT g1) {
  GemmT g = (g1.M > 0 && (int)blockIdx.x >= g1.blkbase) ? g1 : g0;
  __shared__ float At[64 * 132];  // At[k*132 + row]
  __shared__ float Wt[64 * 68];   // Wt[k*68 + j]
  const ushort* As[3] = {g.A0, g.A1, g.A2};
  const float* Ws[3] = {g.W0, g.W1, g.W2};
  const int t = threadIdx.x;
  const int m0 = ((int)blockIdx.x - g.blkbase) * 128;
  const int tc = t & 15;
  const int tr = t >> 4;
  float acc[8][4];
#pragma unroll
  for (int r = 0; r < 8; ++r)
#pragma unroll
    for (int c = 0; c < 4; ++c) acc[r][c] = 0.f;

  for (int s = 0; s < g.nsrc; ++s) {
    if (s) __syncthreads();
    const float* W = Ws[s];
    const float* Wa = (s == g.nsrc - 1) ? g.Wadd : nullptr;
    for (int i = 0; i < 4; ++i) {
      int f = i * 256 + t;
      int j = f & 63;
      int c4 = f >> 6;
      float4 v = *(const float4*)(W + j * 64 + c4 * 4);
      if (Wa) {
        float4 v2 = *(const float4*)(Wa + j * 64 + c4 * 4);
        v.x += v2.x; v.y += v2.y; v.z += v2.z; v.w += v2.w;
      }
      Wt[(c4 * 4 + 0) * 68 + j] = v.x;
      Wt[(c4 * 4 + 1) * 68 + j] = v.y;
      Wt[(c4 * 4 + 2) * 68 + j] = v.z;
      Wt[(c4 * 4 + 3) * 68 + j] = v.w;
    }
    const ushort* A = As[s];
    for (int i = 0; i < 4; ++i) {
      int f = i * 256 + t;   // 1024 chunks of 8 bf16
      int row = f & 127;
      int c8 = f >> 7;       // [0,8)
      int m = m0 + row;
      uint4 u = make_uint4(0, 0, 0, 0);
      if (m < g.M) u = *(const uint4*)(A + (size_t)m * 64 + c8 * 8);
      At[(c8 * 8 + 0) * 132 + row] = bflo(u.x);
      At[(c8 * 8 + 1) * 132 + row] = bfhi(u.x);
      At[(c8 * 8 + 2) * 132 + row] = bflo(u.y);
      At[(c8 * 8 + 3) * 132 + row] = bfhi(u.y);
      At[(c8 * 8 + 4) * 132 + row] = bflo(u.z);
      At[(c8 * 8 + 5) * 132 + row] = bfhi(u.z);
      At[(c8 * 8 + 6) * 132 + row] = bflo(u.w);
      At[(c8 * 8 + 7) * 132 + row] = bfhi(u.w);
    }
    __syncthreads();

#pragma unroll 8
    for (int k = 0; k < 64; ++k) {
      float4 w = *(const float4*)(&Wt[k * 68 + tc * 4]);
      float4 a0 = *(const float4*)(&At[k * 132 + tr * 8]);
      float4 a1 = *(const float4*)(&At[k * 132 + tr * 8 + 4]);
      float av[8] = {a0.x, a0.y, a0.z, a0.w, a1.x, a1.y, a1.z, a1.w};
      float wv[4] = {w.x, w.y, w.z, w.w};
#pragma unroll
      for (int r = 0; r < 8; ++r)
#pragma unroll
        for (int c = 0; c < 4; ++c) acc[r][c] = fmaf(av[r], wv[c], acc[r][c]);
    }
  }

  float4 bv = make_float4(0.f, 0.f, 0.f, 0.f);
  if (g.b0) {
    float4 b0 = *(const float4*)(g.b0 + tc * 4);
    bv.x += b0.x; bv.y += b0.y; bv.z += b0.z; bv.w += b0.w;
  }
  if (g.b1) {
    float4 b1 = *(const float4*)(g.b1 + tc * 4);
    bv.x += b1.x; bv.y += b1.y; bv.z += b1.z; bv.w += b1.w;
  }

  float4 pw = make_float4(0.f, 0.f, 0.f, 0.f);
  float pb = 0.f;
  if (g.projOut) {
    pw = *(const float4*)(g.projW + tc * 4);
    pb = g.projb[0];
  }

#pragma unroll
  for (int r = 0; r < 8; ++r) {
    int m = m0 + tr * 8 + r;
    if (m < g.M) {
      float4 o;
      o.x = fmaxf(acc[r][0] + bv.x, 0.f);
      o.y = fmaxf(acc[r][1] + bv.y, 0.f);
      o.z = fmaxf(acc[r][2] + bv.z, 0.f);
      o.w = fmaxf(acc[r][3] + bv.w, 0.f);
      if (g.projOut) {
        float p = o.x * pw.x + o.y * pw.y + o.z * pw.z + o.w * pw.w;
        p += __shfl_xor(p, 1, 64);
        p += __shfl_xor(p, 2, 64);
        p += __shfl_xor(p, 4, 64);
        p += __shfl_xor(p, 8, 64);
        if (tc == 0) g.projOut[m] = p + pb;
      } else {
        ushort4 ob;
        ob.x = f2bf(o.x); ob.y = f2bf(o.y); ob.z = f2bf(o.z); ob.w = f2bf(o.w);
        *(ushort4*)(g.outB + (size_t)m * 64 + tc * 4) = ob;
      }
    }
  }
}

// ---------------- launch ----------------

extern "C" void kernel_launch(void* const* d_in, const int* in_sizes, int n_in, void* d_out,
                              int out_size, void* d_ws, size_t ws_size, hipStream_t stream) {
  const float* x_person = (const float*)d_in[0];
  const float* x_movie = (const float*)d_in[1];
  const int* acted_src = (const int*)d_in[2];
  const int* acted_dst = (const int*)d_in[3];
  const int* directed_src = (const int*)d_in[4];
  const int* directed_dst = (const int*)d_in[5];
  const int* www_src = (const int*)d_in[6];
  const int* www_dst = (const int*)d_in[7];
  const float* Wl_acted = (const float*)d_in[8];
  const float* bl_acted = (const float*)d_in[9];
  const float* Wr_acted = (const float*)d_in[10];
  const float* Wl_directed = (const float*)d_in[11];
  const float* bl_directed = (const float*)d_in[12];
  const float* Wr_directed = (const float*)d_in[13];
  const float* Wl_www = (const float*)d_in[14];
  const float* bl_www = (const float*)d_in[15];
  const float* Wr_www = (const float*)d_in[16];
  const float* lin_W = (const float*)d_in[17];
  const float* lin_b = (const float*)d_in[18];
  float* out = (float*)d_out;
  (void)in_sizes; (void)n_in; (void)out_size; (void)ws_size;

  char* base = (char*)d_ws;
  size_t pos = 0;
  auto carve = [&](size_t b) -> void* {
    void* r = base + pos;
    pos += (b + 255) & ~(size_t)255;
    return r;
  };
  int* off_a = (int*)carve((N_MOVIE + 1) * sizeof(int));
  int* off_d = (int*)carve((N_MOVIE + 1) * sizeof(int));
  int* off_w = (int*)carve((N_PERSON + 1) * sizeof(int));
  int* parts = (int*)carve(1024 * sizeof(int));
  int* csr_all = (int*)carve((size_t)E_TOTAL * sizeof(int));
  int* pairs = (int*)carve((size_t)E_TOTAL * sizeof(int));
  ushort* xpbf = (ushort*)carve((size_t)N_PERSON * H * sizeof(ushort));
  ushort* xmbf = (ushort*)carve((size_t)N_MOVIE * H * sizeof(ushort));
  ushort* xp0bf = (ushort*)carve((size_t)N_PERSON * H * sizeof(ushort));
  ushort* xm0bf = (ushort*)carve((size_t)N_MOVIE * H * sizeof(ushort));
  ushort* meanAbf = (ushort*)carve((size_t)N_MOVIE * H * sizeof(ushort));
  ushort* meanDbf = (ushort*)carve((size_t)N_MOVIE * H * sizeof(ushort));
  ushort* meanWbf = (ushort*)carve((size_t)N_PERSON * H * sizeof(ushort));

  // relation descriptors (A=acted, D=directed, W=www), contiguous in counts/edges
  RelP rA, rD, rW;
  rA.src = acted_src;  rA.dst = acted_dst;  rA.off = off_a;
  rA.E = E_ACTED;      rA.N = N_MOVIE;
  rA.nblk = (E_ACTED + CH - 1) / CH;      rA.nbuk = (N_MOVIE + NBIN - 1) >> SH;
  rD.src = directed_src; rD.dst = directed_dst; rD.off = off_d;
  rD.E = E_DIRECTED;     rD.N = N_MOVIE;
  rD.nblk = (E_DIRECTED + CH - 1) / CH;   rD.nbuk = (N_MOVIE + NBIN - 1) >> SH;
  rW.src = www_src;    rW.dst = www_dst;  rW.off = off_w;
  rW.E = E_WWW;        rW.N = N_PERSON;
  rW.nblk = (E_WWW + CH - 1) / CH;        rW.nbuk = (N_PERSON + NBIN - 1) >> SH;
  rA.blkbase = 0;                 rD.blkbase = rA.nblk;           rW.blkbase = rA.nblk + rD.nblk;
  rA.bukbase = 0;                 rD.bukbase = rA.nbuk;           rW.bukbase = rA.nbuk + rD.nbuk;
  rA.cbase = 0;                   rD.cbase = rA.nbuk * rA.nblk;
  rW.cbase = rD.cbase + rD.nbuk * rD.nblk;
  rA.ebase = 0;                   rD.ebase = E_ACTED;             rW.ebase = E_ACTED + E_DIRECTED;
  const int n_total = rW.cbase + rW.nbuk * rW.nblk;
  const int nblk_total = rW.blkbase + rW.nblk;
  const int nbuk_total = rW.bukbase + rW.nbuk;

  int* counts = (int*)carve((size_t)n_total * sizeof(int));
  int* off_bb = (int*)carve((size_t)(n_total + 1) * sizeof(int));

  // ---- CSR build (all relations in each launch) ----
  part_count_all_k<<<nblk_total, 256, 0, stream>>>(rA, rD, rW, counts);
  int nb = (n_total + 1023) / 1024;
  scan_block_k<<<nb, 1024, 0, stream>>>(counts, n_total, off_bb, parts);
  scan_block_k<<<1, 1024, 0, stream>>>(parts, nb, parts, nullptr);
  add_off_k<<<(n_total + 1 + 1023) / 1024, 1024, 0, stream>>>(off_bb, n_total, parts, E_TOTAL);
  part_scatter_all_k<<<nblk_total, 256, 0, stream>>>(rA, rD, rW, off_bb, pairs);
  fine_sort_all_k<<<nbuk_total, 1024, 0, stream>>>(rA, rD, rW, off_bb, pairs, csr_all);

  // ---- bf16 casts ----
  cast_all_k<<<2048, 256, 0, stream>>>(x_person, xpbf, N_PERSON * H / 4, x_movie, xmbf,
                                       N_MOVIE * H / 4);

  // 32 dsts per block (4 waves x 8 dsts)
  const int nbA = (N_MOVIE + 31) / 32, nbD = (N_MOVIE + 31) / 32, nbW = (N_PERSON + 31) / 32;
  const int gmM = (N_MOVIE + 127) / 128, gmP = (N_PERSON + 127) / 128;

  // ---- layer 1 pulls: acted, directed, www from xpbf ----
  {
    PullT pA = {xpbf, off_a, meanAbf, N_MOVIE, 0};
    PullT pD = {xpbf, off_d, meanDbf, N_MOVIE, nbA};
    PullT pW = {xpbf, off_w, meanWbf, N_PERSON, nbA + nbD};
    pull_all_k<<<nbA + nbD + nbW, 256, 0, stream>>>(pA, pD, pW, csr_all);
  }
  // ---- layer 1 GEMMs: movie (3 srcs) + person (2 srcs), one launch ----
  {
    GemmT gM = {meanAbf, meanDbf, xmbf,
                Wl_acted, Wl_directed, Wr_acted, Wr_directed, bl_acted, bl_directed,
                xm0bf, nullptr, nullptr, nullptr, N_MOVIE, 3, 0};
    GemmT gP = {meanWbf, xpbf, nullptr,
                Wl_www, Wr_www, nullptr, nullptr, bl_www, nullptr,
                xp0bf, nullptr, nullptr, nullptr, N_PERSON, 2, gmM};
    gemm_all_k<<<gmM + gmP, 256, 0, stream>>>(gM, gP);
  }
  // ---- layer 2 pulls: acted, directed from xp0bf ----
  {
    PullT pA = {xp0bf, off_a, meanAbf, N_MOVIE, 0};
    PullT pD = {xp0bf, off_d, meanDbf, N_MOVIE, nbA};
    PullT pZ = {nullptr, nullptr, nullptr, 0, 0};
    pull_all_k<<<nbA + nbD, 256, 0, stream>>>(pA, pD, pZ, csr_all);
  }
  // ---- layer 2 movie GEMM with fused final projection ----
  {
    GemmT gM = {meanAbf, meanDbf, xm0bf,
                Wl_acted + 4096, Wl_directed + 4096, Wr_acted + 4096, Wr_directed + 4096,
                bl_acted + 64, bl_directed + 64,
                nullptr, lin_W, lin_b, out, N_MOVIE, 3, 0};
    GemmT gZ = {nullptr, nullptr, nullptr, nullptr, nullptr, nullptr, nullptr, nullptr, nullptr,
                nullptr, nullptr, nullptr, nullptr, 0, 0, 0};
    gemm_all_k<<<gmM, 256, 0, stream>>>(gM, gZ);
  }
}